// Round 16
// baseline (1039.917 us; speedup 1.0000x reference)
//
#include <hip/hip_runtime.h>
#include <hip/hip_bf16.h>

typedef __bf16 bf16;
typedef __attribute__((ext_vector_type(8))) __bf16 bf16x8;
typedef __attribute__((ext_vector_type(4))) float floatx4;

#define HDIM 512
#define BATCH 4096
#define TSTEPS 16
#define KA 576      // A width: 63 x-feats + td + 512 h
#define NR 3584     // GEMM1 out cols: 7 roles x 512 h (no pad role)

typedef const __attribute__((address_space(1))) void gvoid;
typedef __attribute__((address_space(3))) void svoid;

// Fast-math forms (validated R7 on attention, R12 on gemm1): single
// v_exp_f32 + v_rcp_f32, no IEEE division chains.
__device__ __forceinline__ float ftanh2(float x) {
  return fmaf(-2.f, __builtin_amdgcn_rcpf(exp2f(x * 2.8853900817779268f) + 1.f), 1.f);
}
__device__ __forceinline__ float fsigm2(float x) {
  return __builtin_amdgcn_rcpf(1.f + exp2f(-x * 1.4426950408889634f));
}

__device__ __forceinline__ float waveAllSum(float v) {
#pragma unroll
  for (int off = 32; off > 0; off >>= 1) v += __shfl_xor(v, off, 64);
  return v;
}

// ---------------------------------------------------------------------------
// Fused GEMM1 + gates. A = [x_t(63) | td | h(512)], B = role-interleaved WcombT
// with NO pad role: packed col n -> blk=n/112, role=(n%112)>>4, h=blk*16+(n&15).
// BM=128, BN=112, BK=64. Waves 1x4 in m (WM=32): TM=2, TN=7 -> all 7 roles of
// (m,h) land in one lane's acc[i][0..6][r]; no cross-wave exchange.
// ROLE SPARSITY: role 4 (tg=WxT) has a zero h-part; roles 5,6 (Wa,We) have a
// zero x-part. kt==0 peeled (roles 0..4); kt>=1 roles {0,1,2,3,5,6}.
// Roles: 0..3 = zi,zf,zo,zc (td*Wt folded via A col63), 4 = tg, 5 = hWa, 6 = hWe.
// ---------------------------------------------------------------------------
__global__ __launch_bounds__(256, 4)
void gemm1_fused(const bf16* __restrict__ A1, const bf16* __restrict__ A2,
                 const bf16* __restrict__ BT,
                 const float* __restrict__ tdT, const float* __restrict__ bvec,
                 const float* __restrict__ WtT, const float* __restrict__ bT,
                 float* __restrict__ cbuf, bf16* __restrict__ hcur,
                 bf16* __restrict__ waSlot, bf16* __restrict__ weSlot) {
  constexpr int BM = 128, BN = 112, BK = 64;
  constexpr int TM = 2, TN = 7;
  __shared__ __align__(16) bf16 As[BM * BK];  // 16 KB
  __shared__ __align__(16) bf16 Bs[BN * BK];  // 14 KB

  const int tid = threadIdx.x;
  const int lane = tid & 63;
  const int wv = tid >> 6;     // m-quadrant (WM=32 each)
  const int quad = lane >> 4;
  const int lr = lane & 15;
  const int bid = blockIdx.x;
  const int xcd = bid & 7;
  const int p = bid >> 3;
  const int n_idx = (xcd << 2) | (p >> 5);  // [0,32): h-group
  const int m_idx = p & 31;
  const int m0 = m_idx * BM;
  const int n0 = n_idx * BN;
  const int g8 = lane >> 3;
  const int cl = (lane & 7) ^ g8;  // logical chunk fetched (phys = lc ^ (row&7))

  floatx4 acc[TM][TN];
#pragma unroll
  for (int i = 0; i < TM; ++i)
#pragma unroll
    for (int j = 0; j < TN; ++j) {
      acc[i][j][0] = 0.f; acc[i][j][1] = 0.f; acc[i][j][2] = 0.f; acc[i][j][3] = 0.f;
    }

  // ---- kt == 0 (x-part, A1): roles 0..4 only; B-groups 0..9 ----
  {
#pragma unroll
    for (int s = 0; s < 4; ++s) {  // A: 16 groups of 8 rows, 4 per wave
      const int g = wv * 4 + s;
      const int r = g * 8 + g8;
      const bf16* src = A1 + (size_t)(m0 + r) * 64 + cl * 8;
      __builtin_amdgcn_global_load_lds((gvoid*)src, (svoid*)&As[g * 512], 16, 0, 0);
    }
#pragma unroll
    for (int s = 0; s < 4; ++s) {  // B: groups 0..9 (roles 0..4)
      const int g = wv * 4 + s;
      if (g < 10) {
        const int r = g * 8 + g8;
        const bf16* src = BT + (size_t)(n0 + r) * KA + cl * 8;
        __builtin_amdgcn_global_load_lds((gvoid*)src, (svoid*)&Bs[g * 512], 16, 0, 0);
      }
    }
    __syncthreads();
#pragma unroll
    for (int s = 0; s < 2; ++s) {  // two K=32 half-steps
      const int lc = s * 4 + quad;
      bf16x8 afr[TM];
      bf16x8 bfr[5];
#pragma unroll
      for (int i = 0; i < TM; ++i) {
        const int r = wv * 32 + i * 16 + lr;
        afr[i] = *reinterpret_cast<const bf16x8*>(&As[r * 64 + ((lc ^ (r & 7)) << 3)]);
      }
#pragma unroll
      for (int j = 0; j < 5; ++j) {
        const int r = j * 16 + lr;
        bfr[j] = *reinterpret_cast<const bf16x8*>(&Bs[r * 64 + ((lc ^ (r & 7)) << 3)]);
      }
#pragma unroll
      for (int i = 0; i < TM; ++i)
#pragma unroll
        for (int j = 0; j < 5; ++j)
          acc[i][j] = __builtin_amdgcn_mfma_f32_16x16x32_bf16(afr[i], bfr[j], acc[i][j], 0, 0, 0);
    }
  }

  // ---- kt = 1..8 (h-part, A2): roles {0,1,2,3,5,6}; B-groups 0..7,10..13 ----
  constexpr int JMAP[6] = {0, 1, 2, 3, 5, 6};
  for (int kt = 1; kt < KA / BK; ++kt) {
    const int kb = kt * BK;
    __syncthreads();
#pragma unroll
    for (int s = 0; s < 4; ++s) {
      const int g = wv * 4 + s;
      const int r = g * 8 + g8;
      const bf16* src = A2 + (size_t)(m0 + r) * 512 + (kb - 64) + cl * 8;
      __builtin_amdgcn_global_load_lds((gvoid*)src, (svoid*)&As[g * 512], 16, 0, 0);
    }
#pragma unroll
    for (int s = 0; s < 4; ++s) {
      const int g = wv * 4 + s;
      if (g < 14 && g != 8 && g != 9) {
        const int r = g * 8 + g8;
        const bf16* src = BT + (size_t)(n0 + r) * KA + kb + cl * 8;
        __builtin_amdgcn_global_load_lds((gvoid*)src, (svoid*)&Bs[g * 512], 16, 0, 0);
      }
    }
    __syncthreads();
#pragma unroll
    for (int s = 0; s < 2; ++s) {
      const int lc = s * 4 + quad;
      bf16x8 afr[TM];
      bf16x8 bfr[6];
#pragma unroll
      for (int i = 0; i < TM; ++i) {
        const int r = wv * 32 + i * 16 + lr;
        afr[i] = *reinterpret_cast<const bf16x8*>(&As[r * 64 + ((lc ^ (r & 7)) << 3)]);
      }
#pragma unroll
      for (int jj = 0; jj < 6; ++jj) {
        const int r = JMAP[jj] * 16 + lr;
        bfr[jj] = *reinterpret_cast<const bf16x8*>(&Bs[r * 64 + ((lc ^ (r & 7)) << 3)]);
      }
#pragma unroll
      for (int i = 0; i < TM; ++i)
#pragma unroll
        for (int jj = 0; jj < 6; ++jj)
          acc[i][JMAP[jj]] =
              __builtin_amdgcn_mfma_f32_16x16x32_bf16(afr[i], bfr[jj], acc[i][JMAP[jj]], 0, 0, 0);
    }
  }

  // ---- fused gate epilogue: all roles in-lane (fast-math) ----
  const int hcol = n_idx * 16 + lr;
  const float bvi = bvec[hcol], bvf = bvec[512 + hcol];
  const float bvo = bvec[1024 + hcol], bvc = bvec[1536 + hcol];
  const float wtt = WtT[hcol], bt_ = bT[hcol];
#pragma unroll
  for (int i = 0; i < TM; ++i) {
#pragma unroll
    for (int r = 0; r < 4; ++r) {
      const int m = m0 + wv * 32 + i * 16 + quad * 4 + r;
      const float td = tdT[m];
      const size_t o = (size_t)m * 512 + hcol;
      const float c_old = cbuf[o];
      const float i_ = fsigm2(acc[i][0][r] + bvi);
      const float f_ = fsigm2(acc[i][1][r] + bvf);
      const float o_ = fsigm2(acc[i][2][r] + bvo);
      const float ch = ftanh2(acc[i][3][r] + bvc);
      const float tg = fsigm2(acc[i][4][r] + fsigm2(td * wtt) + bt_);
      const float cn = f_ * c_old + (i_ + tg) * ch;
      cbuf[o] = cn;
      hcur[o] = (bf16)(o_ * ftanh2(cn));
      waSlot[o] = (bf16)acc[i][5][r];
      weSlot[o] = (bf16)acc[i][6][r];
    }
  }
}

// ---------------------------------------------------------------------------
// GEMM2: hcur[4096x512] @ wbwgT^T -> hWbG bf16 [4096x1024] (+baPad).
// BM=128, BN=64, BK=64, 256 threads (4 waves in m), 512 blocks = 2/CU. (R1 win)
// ---------------------------------------------------------------------------
__global__ __launch_bounds__(256, 4)
void gemm2_kernel(const bf16* __restrict__ hcur, const bf16* __restrict__ wbwgT,
                  const float* __restrict__ baPad, bf16* __restrict__ hWbG) {
  __shared__ __align__(16) bf16 As[128 * 64];  // 16 KB
  __shared__ __align__(16) bf16 Bs[64 * 64];   // 8 KB

  const int tid = threadIdx.x;
  const int lane = tid & 63;
  const int wv = tid >> 6;   // 0..3, m-stripe of 32 rows
  const int quad = lane >> 4;
  const int lr = lane & 15;
  const int bid = blockIdx.x;
  const int m0 = (bid >> 4) * 128;
  const int n0 = (bid & 15) * 64;
  const int g8 = lane >> 3;
  const int cl = (lane & 7) ^ g8;

  floatx4 acc[2][4];
#pragma unroll
  for (int i = 0; i < 2; ++i)
#pragma unroll
    for (int j = 0; j < 4; ++j) {
      acc[i][j][0] = 0.f; acc[i][j][1] = 0.f; acc[i][j][2] = 0.f; acc[i][j][3] = 0.f;
    }

  for (int kt = 0; kt < 8; ++kt) {
    const int kb = kt * 64;
    __syncthreads();
#pragma unroll
    for (int s = 0; s < 4; ++s) {  // A: 16 groups of 8 rows, 4 per wave
      const int g = wv * 4 + s;
      const int r = g * 8 + g8;
      const bf16* src = hcur + (size_t)(m0 + r) * 512 + kb + cl * 8;
      __builtin_amdgcn_global_load_lds((gvoid*)src, (svoid*)&As[g * 512], 16, 0, 0);
    }
#pragma unroll
    for (int s = 0; s < 2; ++s) {  // B: 8 groups of 8 rows, 2 per wave
      const int g = wv * 2 + s;
      const int r = g * 8 + g8;
      const bf16* src = wbwgT + (size_t)(n0 + r) * 512 + kb + cl * 8;
      __builtin_amdgcn_global_load_lds((gvoid*)src, (svoid*)&Bs[g * 512], 16, 0, 0);
    }
    __syncthreads();
#pragma unroll
    for (int s = 0; s < 2; ++s) {
      const int lc = s * 4 + quad;
      bf16x8 afr[2];
      bf16x8 bfr[4];
#pragma unroll
      for (int i = 0; i < 2; ++i) {
        const int r = wv * 32 + i * 16 + lr;
        afr[i] = *reinterpret_cast<const bf16x8*>(&As[r * 64 + ((lc ^ (r & 7)) << 3)]);
      }
#pragma unroll
      for (int j = 0; j < 4; ++j) {
        const int r = j * 16 + lr;
        bfr[j] = *reinterpret_cast<const bf16x8*>(&Bs[r * 64 + ((lc ^ (r & 7)) << 3)]);
      }
#pragma unroll
      for (int i = 0; i < 2; ++i)
#pragma unroll
        for (int j = 0; j < 4; ++j)
          acc[i][j] = __builtin_amdgcn_mfma_f32_16x16x32_bf16(afr[i], bfr[j], acc[i][j], 0, 0, 0);
    }
  }

#pragma unroll
  for (int i = 0; i < 2; ++i) {
#pragma unroll
    for (int j = 0; j < 4; ++j) {
      const int n = n0 + j * 16 + lr;
      const float bb = baPad[n];
#pragma unroll
      for (int r = 0; r < 4; ++r) {
        const int m = m0 + wv * 32 + i * 16 + quad * 4 + r;
        hWbG[(size_t)m * 1024 + n] = (bf16)(acc[i][j][r] + bb);
      }
    }
  }
}

// ---------------------------------------------------------------------------
// Generic MFMA GEMM (glds staging, BK=32 swizzle) — head only.
// mode 3: relu(v+cBias2) -> bf16 outBa
// ---------------------------------------------------------------------------
template <int BM, int BN>
__global__ __launch_bounds__(256)
void gemm_glds_kernel(const bf16* __restrict__ A1, int ld1, int K1,
                      const bf16* __restrict__ A2, int ld2,
                      const bf16* __restrict__ BT, int K, int mode,
                      float* __restrict__ outF, int ldF, const float* __restrict__ colBias,
                      bf16* __restrict__ outBa, int ldBa, const float* __restrict__ cBias2) {
  constexpr int BK = 32;
  constexpr int WM = BM / 2;
  constexpr int WN = BN / 2;
  constexpr int TM = WM / 16;
  constexpr int TN = WN / 16;
  constexpr int AIW = BM / 64;
  constexpr int BIW = BN / 64;
  __shared__ __align__(16) bf16 As[BM * BK];
  __shared__ __align__(16) bf16 Bs[BN * BK];

  const int tid = threadIdx.x;
  const int lane = tid & 63;
  const int wv = tid >> 6;
  const int wy = wv >> 1;
  const int wx = wv & 1;
  const int quad = lane >> 4;
  const int lr = lane & 15;
  const int m0 = blockIdx.y * BM;
  const int n0 = blockIdx.x * BN;
  const int sw = quad ^ ((lr >> 1) & 3);
  const int srow = lane >> 2;
  const int cl = (lane & 3) ^ ((lane >> 3) & 3);

  floatx4 acc[TM][TN];
#pragma unroll
  for (int i = 0; i < TM; ++i)
#pragma unroll
    for (int j = 0; j < TN; ++j) {
      acc[i][j][0] = 0.f; acc[i][j][1] = 0.f; acc[i][j][2] = 0.f; acc[i][j][3] = 0.f;
    }

  const int kTiles = K / BK;
  for (int kt = 0; kt < kTiles; ++kt) {
    const int kb = kt * BK;
    __syncthreads();
#pragma unroll
    for (int s = 0; s < AIW; ++s) {
      const int rbase = (wv * AIW + s) * 16;
      const int r = rbase + srow;
      const int col = kb + cl * 8;
      const bf16* src = (col < K1) ? (A1 + (size_t)(m0 + r) * ld1 + col)
                                   : (A2 + (size_t)(m0 + r) * ld2 + (col - K1));
      __builtin_amdgcn_global_load_lds((gvoid*)src, (svoid*)&As[rbase * BK], 16, 0, 0);
    }
#pragma unroll
    for (int s = 0; s < BIW; ++s) {
      const int rbase = (wv * BIW + s) * 16;
      const int r = rbase + srow;
      const bf16* src = BT + (size_t)(n0 + r) * K + kb + cl * 8;
      __builtin_amdgcn_global_load_lds((gvoid*)src, (svoid*)&Bs[rbase * BK], 16, 0, 0);
    }
    __syncthreads();
    bf16x8 afr[TM];
    bf16x8 bfr[TN];
#pragma unroll
    for (int i = 0; i < TM; ++i)
      afr[i] = *reinterpret_cast<const bf16x8*>(&As[(wy * WM + i * 16 + lr) * BK + sw * 8]);
#pragma unroll
    for (int j = 0; j < TN; ++j)
      bfr[j] = *reinterpret_cast<const bf16x8*>(&Bs[(wx * WN + j * 16 + lr) * BK + sw * 8]);
#pragma unroll
    for (int i = 0; i < TM; ++i)
#pragma unroll
      for (int j = 0; j < TN; ++j)
        acc[i][j] = __builtin_amdgcn_mfma_f32_16x16x32_bf16(afr[i], bfr[j], acc[i][j], 0, 0, 0);
  }

#pragma unroll
  for (int i = 0; i < TM; ++i) {
#pragma unroll
    for (int j = 0; j < TN; ++j) {
#pragma unroll
      for (int r = 0; r < 4; ++r) {
        int m = m0 + wy * WM + i * 16 + quad * 4 + r;
        int n = n0 + wx * WN + j * 16 + lr;
        float v = acc[i][j][r];
        if (mode == 0) {
          if (colBias != nullptr) v += colBias[n];
          outF[(size_t)m * ldF + n] = v;
        } else {  // mode 3
          v += cBias2[n];
          v = v > 0.f ? v : 0.f;
          outBa[(size_t)m * ldBa + n] = (bf16)v;
        }
      }
    }
  }
}

// ---------------------------------------------------------------------------
// Setup kernels (run every call; ws re-poisoned by harness)
// ---------------------------------------------------------------------------
// Packed WcombT[n][k], n<3584: blk=n/112, role=(n%112)>>4, h=blk*16+(n&15)
__global__ void pack_wcombT_kernel(const float* __restrict__ Wx, const float* __restrict__ Uh,
                                   const float* __restrict__ Wt, const float* __restrict__ WxT,
                                   const float* __restrict__ Wa, const float* __restrict__ We,
                                   bf16* __restrict__ out) {
  int idx = blockIdx.x * 256 + threadIdx.x;
  if (idx >= NR * KA) return;
  int n = idx / KA;
  int k = idx - n * KA;
  int blk = n / 112;
  int rem = n - blk * 112;
  int role = rem >> 4;
  int h = blk * 16 + (rem & 15);
  float v = 0.f;
  if (k < 63) {
    if (role < 4) v = Wx[k * 2048 + role * 512 + h];
    else if (role == 4) v = WxT[k * 512 + h];
  } else if (k == 63) {
    if (role < 3) v = Wt[role * 512 + h];
  } else {
    int kh = k - 64;
    if (role < 4) v = Uh[kh * 2048 + role * 512 + h];
    else if (role == 5) v = Wa[kh * 512 + h];
    else if (role == 6) v = We[kh * 512 + h];
  }
  out[idx] = (bf16)v;
}

__global__ void pack_t_kernel(const float* __restrict__ in, bf16* __restrict__ out, int N, int K) {
  int idx = blockIdx.x * 256 + threadIdx.x;
  if (idx >= N * K) return;
  int n = idx / K;
  int j = idx - n * K;
  out[idx] = (bf16)in[(size_t)j * N + n];
}

__global__ __launch_bounds__(512)
void setup_misc_kernel(const float* __restrict__ init_proj, const float* __restrict__ Wa,
                       const float* __restrict__ We, const float* __restrict__ ba,
                       float* __restrict__ sWa, float* __restrict__ sWe,
                       float* __restrict__ baPad) {
  __shared__ float s_sh[HDIM];
  int h = threadIdx.x;
  float acc = 0.f;
  for (int f = 0; f < 64; ++f) acc += init_proj[f * HDIM + h];
  s_sh[h] = acc;
  baPad[h] = ba[h];
  baPad[HDIM + h] = 0.f;
  __syncthreads();
  float a2 = 0.f, a3 = 0.f;
  for (int i = 0; i < HDIM; ++i) {
    a2 += s_sh[i] * Wa[i * HDIM + h];
    a3 += s_sh[i] * We[i * HDIM + h];
  }
  sWa[h] = a2;
  sWe[h] = a3;
}

__global__ void zero_state_kernel(float* __restrict__ c, bf16* __restrict__ h) {
  int idx = blockIdx.x * 256 + threadIdx.x;
  if (idx >= BATCH * HDIM) return;
  c[idx] = 0.f;
  h[idx] = (bf16)0.f;
}

__global__ void build_x_kernel(const float* __restrict__ inputs, bf16* __restrict__ xbuf,
                               float* __restrict__ tdT) {
  int idx = blockIdx.x * 256 + threadIdx.x;
  if (idx >= TSTEPS * BATCH * 64) return;
  int c = idx & 63;
  int bt = idx >> 6;
  int t = bt >> 12;
  int b = bt & 4095;
  float v;
  if (c < 63) {
    v = inputs[(size_t)b * 1024 + t * 64 + 1 + c];
  } else {
    v = inputs[(size_t)b * 1024 + t * 64];
    tdT[t * BATCH + b] = v;
  }
  xbuf[idx] = (bf16)v;
}

// ---------------------------------------------------------------------------
// Attention + h_new epilogue (R15: wave-pair row split for 2x TLP).
// R8's pipeline was correct but grid-capped at 16 waves/CU (1 row/wave, 1024
// blocks). Now each row is split across a WAVE PAIR: half=0 takes even j's,
// half=1 odd j's (full 512-col rows, bf16x8 loads unchanged). Each wave runs
// the R8 chunk pipeline over its <=8 rows, butterflies its own q's (full dot
// within one wave), publishes via 128B LDS; softmax duplicated per wave;
// pass-2 partial cx combined via conflict-free i-major LDS exchange.
// Grid 2048 blocks -> 8 blocks/CU available; ~80-95 VGPR -> 20-24 waves/CU.
// stg[] reused across passes (abuf dead before ebuf chunk-0 issue).
// ---------------------------------------------------------------------------
template <int K>
__global__ __launch_bounds__(256, 5)
void attention_kernel(const bf16* __restrict__ hWbG,
                      const float* __restrict__ sWa, const float* __restrict__ sWe,
                      const float* __restrict__ va, const float* __restrict__ bh,
                      const bf16* __restrict__ histWa, const bf16* __restrict__ histWe,
                      bf16* __restrict__ hbuf) {
  constexpr float C = 2.8853900817779268f;   // 2*log2(e)
  constexpr float L2E = 1.4426950408889634f; // log2(e)
  constexpr int CH = 4;
  constexpr int MAXJ = (K + 1) / 2;          // max rows per half-wave
  constexpr int NC = (MAXJ + CH - 1) / CH;   // chunks (0 when K==0)
  __shared__ float qsh[2][16];
  __shared__ float cxsh[2][8 * 64];          // i-major: [i*64+lane], conflict-free

  const int tid = threadIdx.x;
  const int lane = tid & 63;
  const int wv = tid >> 6;      // 0..3
  const int br = wv >> 1;       // row within block (0,1)
  const int half = wv & 1;      // even/odd j's
  const int b = blockIdx.x * 2 + br;

  const bf16* wbp = hWbG + (size_t)b * 1024 + lane * 8;
  bf16x8 wbv = *reinterpret_cast<const bf16x8*>(wbp);
  bf16x8 wgv = *reinterpret_cast<const bf16x8*>(wbp + 512);

  const bf16* pa = histWa + (size_t)b * HDIM + lane * 8;  // + j*BATCH*HDIM per row
  const bf16* pe = histWe + (size_t)b * HDIM + lane * 8;
  constexpr size_t RSTR = (size_t)BATCH * HDIM;

  bf16x8 stg[2][CH];
  // prologue: issue this wave's chunk 0 of histWa (j = half + 2*jj)
  if (NC > 0) {
#pragma unroll
    for (int r = 0; r < CH; ++r) {
      if (r < MAXJ) {
        const int j = half + 2 * r;
        if (j < K) stg[0][r] = *reinterpret_cast<const bf16x8*>(pa + (size_t)j * RSTR);
      }
    }
    asm volatile("" ::: "memory");
  }

  float wb2[8], vv[8];
  float svv = 0.f;
#pragma unroll
  for (int i = 0; i < 8; ++i) {
    wb2[i] = (float)wbv[i] * C;
    vv[i] = va[lane * 8 + i];
    svv += vv[i];
  }

  // e_init (only when K < 15) — duplicated per wave, computed under load latency
  float e_init = 0.f;
  if (K < 15) {
    float p = 0.f;
#pragma unroll
    for (int i = 0; i < 8; ++i) {
      float r = __builtin_amdgcn_rcpf(exp2f(fmaf(sWa[lane * 8 + i], C, wb2[i])) + 1.f);
      p = fmaf(vv[i], r, p);
    }
    e_init = waveAllSum(fmaf(-2.f, p, svv));
  }

  // ---- pass 1 pipelined over this wave's j-list ----
  float q[MAXJ > 0 ? MAXJ : 1];
#pragma unroll
  for (int c = 0; c < NC; ++c) {
    if (c + 1 < NC) {
#pragma unroll
      for (int r = 0; r < CH; ++r) {
        const int jj = (c + 1) * CH + r;
        if (jj < MAXJ) {
          const int j = half + 2 * jj;
          if (j < K)
            stg[(c + 1) & 1][r] = *reinterpret_cast<const bf16x8*>(pa + (size_t)j * RSTR);
        }
      }
      asm volatile("" ::: "memory");
    }
#pragma unroll
    for (int r = 0; r < CH; ++r) {
      const int jj = c * CH + r;
      if (jj < MAXJ) {
        const int j = half + 2 * jj;
        if (j < K) {
          float p = 0.f;
#pragma unroll
          for (int i = 0; i < 8; ++i) {
            float t = __builtin_amdgcn_rcpf(
                exp2f(fmaf((float)stg[c & 1][r][i], C, wb2[i])) + 1.f);
            p = fmaf(vv[i], t, p);
          }
          q[jj] = fmaf(-2.f, p, svv);
        }
      }
    }
  }

  // ---- issue hve chunk 0 (reuse stg; abuf dead); butterfly covers latency ----
  if (NC > 0) {
#pragma unroll
    for (int r = 0; r < CH; ++r) {
      if (r < MAXJ) {
        const int j = half + 2 * r;
        if (j < K) stg[0][r] = *reinterpret_cast<const bf16x8*>(pe + (size_t)j * RSTR);
      }
    }
    asm volatile("" ::: "memory");
  }

  // joint butterfly over this wave's q's (wave-uniform guards)
#pragma unroll
  for (int off = 32; off > 0; off >>= 1) {
#pragma unroll
    for (int jj = 0; jj < MAXJ; ++jj)
      if (half + 2 * jj < K) q[jj] += __shfl_xor(q[jj], off, 64);
  }

  // publish q's (wave-uniform after butterfly)
  if (lane == 0) {
#pragma unroll
    for (int jj = 0; jj < MAXJ; ++jj) {
      const int j = half + 2 * jj;
      if (j < K) qsh[br][j] = q[jj];
    }
  }
  __syncthreads();

  // ---- softmax over {init x (15-K), all K q's} (duplicated per wave) ----
  float mx = (K < 15) ? e_init : -1e30f;
#pragma unroll
  for (int j = 0; j < K; ++j) mx = fmaxf(mx, qsh[br][j]);
  float winit = (K < 15) ? (float)(15 - K) * exp2f((e_init - mx) * L2E) : 0.f;
  float denom = winit;
#pragma unroll
  for (int j = 0; j < K; ++j) denom += exp2f((qsh[br][j] - mx) * L2E);
  const float inv = __builtin_amdgcn_rcpf(denom);

  // ---- pass 2 pipelined: weighted sum of this wave's hve rows ----
  float cx[8];
  if (half == 0) {
    const float ai = winit * inv;
#pragma unroll
    for (int i = 0; i < 8; ++i) cx[i] = ai * sWe[lane * 8 + i];
  } else {
#pragma unroll
    for (int i = 0; i < 8; ++i) cx[i] = 0.f;
  }
#pragma unroll
  for (int c = 0; c < NC; ++c) {
    if (c + 1 < NC) {
#pragma unroll
      for (int r = 0; r < CH; ++r) {
        const int jj = (c + 1) * CH + r;
        if (jj < MAXJ) {
          const int j = half + 2 * jj;
          if (j < K)
            stg[(c + 1) & 1][r] = *reinterpret_cast<const bf16x8*>(pe + (size_t)j * RSTR);
        }
      }
      asm volatile("" ::: "memory");
    }
#pragma unroll
    for (int r = 0; r < CH; ++r) {
      const int jj = c * CH + r;
      if (jj < MAXJ) {
        const int j = half + 2 * jj;
        if (j < K) {
          const float aj = exp2f((qsh[br][j] - mx) * L2E) * inv;
#pragma unroll
          for (int i = 0; i < 8; ++i) cx[i] = fmaf(aj, (float)stg[c & 1][r][i], cx[i]);
        }
      }
    }
  }

  // ---- combine partials across the wave pair ----
  if (half == 1) {
#pragma unroll
    for (int i = 0; i < 8; ++i) cxsh[br][i * 64 + lane] = cx[i];
  }
  __syncthreads();
  if (half == 0) {
    bf16x8 hnew;
#pragma unroll
    for (int i = 0; i < 8; ++i) {
      float s = cx[i] + cxsh[br][i * 64 + lane] + (float)wgv[i] + bh[lane * 8 + i];
      float r = __builtin_amdgcn_rcpf(exp2f(s * C) + 1.f);
      hnew[i] = (bf16)fmaf(-2.f, r, 1.f);
    }
    *reinterpret_cast<bf16x8*>(hbuf + (size_t)b * HDIM + lane * 8) = hnew;
  }
}

__global__ __launch_bounds__(256)
void head_kernel(const bf16* __restrict__ hd1, const float* __restrict__ W2,
                 const float* __restrict__ b2, const float* __restrict__ W3,
                 const float* __restrict__ b3, float* __restrict__ out) {
  __shared__ float W2s[256 * 32];
  __shared__ float b2s[32];
  __shared__ float W3s[64];
  __shared__ float b3s[2];
  for (int i = threadIdx.x; i < 256 * 32; i += 256) W2s[i] = W2[i];
  if (threadIdx.x < 32) b2s[threadIdx.x] = b2[threadIdx.x];
  if (threadIdx.x < 64) W3s[threadIdx.x] = W3[threadIdx.x];
  if (threadIdx.x < 2) b3s[threadIdx.x] = b3[threadIdx.x];
  __syncthreads();
  int row = blockIdx.x * 256 + threadIdx.x;
  float acc[32];
#pragma unroll
  for (int j = 0; j < 32; ++j) acc[j] = b2s[j];
  const bf16* hp = hd1 + (size_t)row * 256;
  for (int i = 0; i < 256; ++i) {
    float hv = (float)hp[i];
#pragma unroll
    for (int j = 0; j < 32; ++j) acc[j] += hv * W2s[i * 32 + j];
  }
  float l0 = b3s[0], l1 = b3s[1];
#pragma unroll
  for (int j = 0; j < 32; ++j) {
    float r = fmaxf(acc[j], 0.f);
    l0 += r * W3s[j * 2];
    l1 += r * W3s[j * 2 + 1];
  }
  float m = fmaxf(l0, l1);
  float e0 = __expf(l0 - m), e1 = __expf(l1 - m);
  float inv = 1.f / (e0 + e1);
  out[(size_t)row * 2] = e0 * inv;
  out[(size_t)row * 2 + 1] = e1 * inv;
}

// ---------------------------------------------------------------------------
extern "C" void kernel_launch(void* const* d_in, const int* in_sizes, int n_in,
                              void* d_out, int out_size, void* d_ws, size_t ws_size,
                              hipStream_t stream) {
  const float* inputs    = (const float*)d_in[0];
  const float* init_proj = (const float*)d_in[1];
  const float* Wx  = (const float*)d_in[3];
  const float* Uh  = (const float*)d_in[4];
  const float* Wt  = (const float*)d_in[5];
  const float* bv  = (const float*)d_in[6];
  const float* WxT = (const float*)d_in[7];
  const float* WtT = (const float*)d_in[8];
  const float* bT  = (const float*)d_in[9];
  const float* Wa  = (const float*)d_in[10];
  const float* Wb  = (const float*)d_in[11];
  const float* va  = (const float*)d_in[12];
  const float* ba  = (const float*)d_in[13];
  const float* We  = (const float*)d_in[14];
  const float* Wg  = (const float*)d_in[15];
  const float* bh  = (const float*)d_in[16];
  const float* W1  = (const float*)d_in[17];
  const float* b1  = (const float*)d_in[18];
  const float* W2  = (const float*)d_in[19];
  const float* b2  = (const float*)d_in[20];
  const float* W3  = (const float*)d_in[21];
  const float* b3  = (const float*)d_in[22];
  float* out = (float*)d_out;

  char* wp = (char*)d_ws;
  auto carve = [&](size_t bytes) -> void* {
    void* p = (void*)wp;
    wp += (bytes + 255) & ~(size_t)255;
    return p;
  };
  bf16* wcombT = (bf16*)carve((size_t)NR * KA * 2);
  bf16* wbwgT  = (bf16*)carve((size_t)1024 * 512 * 2);
  bf16* w1T    = (bf16*)carve((size_t)256 * 512 * 2);
  float* sWa   = (float*)carve(512 * 4);
  float* sWe   = (float*)carve(512 * 4);
  float* baPad = (float*)carve(1024 * 4);
  bf16* xbuf   = (bf16*)carve((size_t)TSTEPS * BATCH * 64 * 2);
  float* tdT   = (float*)carve((size_t)TSTEPS * BATCH * 4);
  float* cbuf  = (float*)carve((size_t)BATCH * HDIM * 4);
  bf16* hbuf   = (bf16*)carve((size_t)BATCH * HDIM * 2);
  bf16* hcur   = (bf16*)carve((size_t)BATCH * HDIM * 2);
  bf16* hWbG   = (bf16*)carve((size_t)BATCH * 1024 * 2);
  bf16* histWa = (bf16*)carve((size_t)16 * BATCH * HDIM * 2);
  bf16* histWe = (bf16*)carve((size_t)16 * BATCH * HDIM * 2);
  bf16* hd1    = (bf16*)carve((size_t)BATCH * 256 * 2);

  // ---- setup ----
  build_x_kernel<<<(TSTEPS * BATCH * 64) / 256, 256, 0, stream>>>(inputs, xbuf, tdT);
  pack_wcombT_kernel<<<(NR * KA + 255) / 256, 256, 0, stream>>>(Wx, Uh, Wt, WxT, Wa, We, wcombT);
  pack_t_kernel<<<(512 * 512) / 256, 256, 0, stream>>>(Wb, wbwgT, 512, 512);
  pack_t_kernel<<<(512 * 512) / 256, 256, 0, stream>>>(Wg, wbwgT + (size_t)512 * 512, 512, 512);
  pack_t_kernel<<<(256 * 512) / 256, 256, 0, stream>>>(W1, w1T, 256, 512);
  setup_misc_kernel<<<1, 512, 0, stream>>>(init_proj, Wa, We, ba, sWa, sWe, baPad);
  zero_state_kernel<<<(BATCH * HDIM) / 256, 256, 0, stream>>>(cbuf, hbuf);

  // ---- recurrence: 3 kernels per step ----
#define ATTN_LAUNCH(KK)                                                              \
  case KK:                                                                           \
    attention_kernel<KK><<<BATCH / 2, 256, 0, stream>>>(hWbG, sWa, sWe, va, bh,      \
                                                        histWa, histWe, hbuf);       \
    break;

  for (int t = 0; t < TSTEPS; ++t) {
    bf16* waSlot = histWa + (size_t)((t + 15) & 15) * BATCH * HDIM;
    bf16* weSlot = histWe + (size_t)((t + 15) & 15) * BATCH * HDIM;
    gemm1_fused<<<1024, 256, 0, stream>>>(
        xbuf + (size_t)t * BATCH * 64, hbuf, wcombT, tdT + (size_t)t * BATCH, bv, WtT, bT,
        cbuf, hcur, waSlot, weSlot);
    gemm2_kernel<<<512, 256, 0, stream>>>(hcur, wbwgT, baPad, hWbG);
    switch (t) {
      ATTN_LAUNCH(0) ATTN_LAUNCH(1) ATTN_LAUNCH(2) ATTN_LAUNCH(3)
      ATTN_LAUNCH(4) ATTN_LAUNCH(5) ATTN_LAUNCH(6) ATTN_LAUNCH(7)
      ATTN_LAUNCH(8) ATTN_LAUNCH(9) ATTN_LAUNCH(10) ATTN_LAUNCH(11)
      ATTN_LAUNCH(12) ATTN_LAUNCH(13) ATTN_LAUNCH(14) ATTN_LAUNCH(15)
    }
  }
#undef ATTN_LAUNCH

  // ---- head ----
  gemm_glds_kernel<64, 128><<<dim3(256 / 128, BATCH / 64), 256, 0, stream>>>(
      hbuf, 512, 512, hbuf, 512, w1T, 512, 3, nullptr, 0, nullptr, hd1, 256, b1);
  head_kernel<<<BATCH / 256, 256, 0, stream>>>(hd1, W2, b2, W3, b3, out);
}

// Round 17
// 972.885 us; speedup vs baseline: 1.0689x; 1.0689x over previous
//
#include <hip/hip_runtime.h>
#include <hip/hip_bf16.h>

typedef __bf16 bf16;
typedef __attribute__((ext_vector_type(8))) __bf16 bf16x8;
typedef __attribute__((ext_vector_type(4))) float floatx4;

#define HDIM 512
#define BATCH 4096
#define TSTEPS 16
#define KA 576      // A width: 63 x-feats + td + 512 h
#define NR 3584     // GEMM1 out cols: 7 roles x 512 h (no pad role)

typedef const __attribute__((address_space(1))) void gvoid;
typedef __attribute__((address_space(3))) void svoid;

// Fast-math forms (validated R7 on attention, R13 on gemm1): single
// v_exp_f32 + v_rcp_f32, no IEEE division chains.
__device__ __forceinline__ float ftanh2(float x) {
  return fmaf(-2.f, __builtin_amdgcn_rcpf(exp2f(x * 2.8853900817779268f) + 1.f), 1.f);
}
__device__ __forceinline__ float fsigm2(float x) {
  return __builtin_amdgcn_rcpf(1.f + exp2f(-x * 1.4426950408889634f));
}

__device__ __forceinline__ float waveAllSum(float v) {
#pragma unroll
  for (int off = 32; off > 0; off >>= 1) v += __shfl_xor(v, off, 64);
  return v;
}

// ---------------------------------------------------------------------------
// Fused GEMM1 + gates. A = [x_t(63) | td | h(512)], B = role-interleaved WcombT
// with NO pad role: packed col n -> blk=n/112, role=(n%112)>>4, h=blk*16+(n&15).
// BM=128, BN=112, BK=64. Waves 1x4 in m (WM=32): TM=2, TN=7 -> all 7 roles of
// (m,h) land in one lane's acc[i][0..6][r]; no cross-wave exchange.
// ROLE SPARSITY: role 4 (tg=WxT) has a zero h-part; roles 5,6 (Wa,We) have a
// zero x-part. kt==0 peeled (roles 0..4); kt>=1 roles {0,1,2,3,5,6}.
// Roles: 0..3 = zi,zf,zo,zc (td*Wt folded via A col63), 4 = tg, 5 = hWa, 6 = hWe.
// ---------------------------------------------------------------------------
__global__ __launch_bounds__(256, 4)
void gemm1_fused(const bf16* __restrict__ A1, const bf16* __restrict__ A2,
                 const bf16* __restrict__ BT,
                 const float* __restrict__ tdT, const float* __restrict__ bvec,
                 const float* __restrict__ WtT, const float* __restrict__ bT,
                 float* __restrict__ cbuf, bf16* __restrict__ hcur,
                 bf16* __restrict__ waSlot, bf16* __restrict__ weSlot) {
  constexpr int BM = 128, BN = 112, BK = 64;
  constexpr int TM = 2, TN = 7;
  __shared__ __align__(16) bf16 As[BM * BK];  // 16 KB
  __shared__ __align__(16) bf16 Bs[BN * BK];  // 14 KB

  const int tid = threadIdx.x;
  const int lane = tid & 63;
  const int wv = tid >> 6;     // m-quadrant (WM=32 each)
  const int quad = lane >> 4;
  const int lr = lane & 15;
  const int bid = blockIdx.x;
  const int xcd = bid & 7;
  const int p = bid >> 3;
  const int n_idx = (xcd << 2) | (p >> 5);  // [0,32): h-group
  const int m_idx = p & 31;
  const int m0 = m_idx * BM;
  const int n0 = n_idx * BN;
  const int g8 = lane >> 3;
  const int cl = (lane & 7) ^ g8;  // logical chunk fetched (phys = lc ^ (row&7))

  floatx4 acc[TM][TN];
#pragma unroll
  for (int i = 0; i < TM; ++i)
#pragma unroll
    for (int j = 0; j < TN; ++j) {
      acc[i][j][0] = 0.f; acc[i][j][1] = 0.f; acc[i][j][2] = 0.f; acc[i][j][3] = 0.f;
    }

  // ---- kt == 0 (x-part, A1): roles 0..4 only; B-groups 0..9 ----
  {
#pragma unroll
    for (int s = 0; s < 4; ++s) {  // A: 16 groups of 8 rows, 4 per wave
      const int g = wv * 4 + s;
      const int r = g * 8 + g8;
      const bf16* src = A1 + (size_t)(m0 + r) * 64 + cl * 8;
      __builtin_amdgcn_global_load_lds((gvoid*)src, (svoid*)&As[g * 512], 16, 0, 0);
    }
#pragma unroll
    for (int s = 0; s < 4; ++s) {  // B: groups 0..9 (roles 0..4)
      const int g = wv * 4 + s;
      if (g < 10) {
        const int r = g * 8 + g8;
        const bf16* src = BT + (size_t)(n0 + r) * KA + cl * 8;
        __builtin_amdgcn_global_load_lds((gvoid*)src, (svoid*)&Bs[g * 512], 16, 0, 0);
      }
    }
    __syncthreads();
#pragma unroll
    for (int s = 0; s < 2; ++s) {  // two K=32 half-steps
      const int lc = s * 4 + quad;
      bf16x8 afr[TM];
      bf16x8 bfr[5];
#pragma unroll
      for (int i = 0; i < TM; ++i) {
        const int r = wv * 32 + i * 16 + lr;
        afr[i] = *reinterpret_cast<const bf16x8*>(&As[r * 64 + ((lc ^ (r & 7)) << 3)]);
      }
#pragma unroll
      for (int j = 0; j < 5; ++j) {
        const int r = j * 16 + lr;
        bfr[j] = *reinterpret_cast<const bf16x8*>(&Bs[r * 64 + ((lc ^ (r & 7)) << 3)]);
      }
#pragma unroll
      for (int i = 0; i < TM; ++i)
#pragma unroll
        for (int j = 0; j < 5; ++j)
          acc[i][j] = __builtin_amdgcn_mfma_f32_16x16x32_bf16(afr[i], bfr[j], acc[i][j], 0, 0, 0);
    }
  }

  // ---- kt = 1..8 (h-part, A2): roles {0,1,2,3,5,6}; B-groups 0..7,10..13 ----
  constexpr int JMAP[6] = {0, 1, 2, 3, 5, 6};
  for (int kt = 1; kt < KA / BK; ++kt) {
    const int kb = kt * BK;
    __syncthreads();
#pragma unroll
    for (int s = 0; s < 4; ++s) {
      const int g = wv * 4 + s;
      const int r = g * 8 + g8;
      const bf16* src = A2 + (size_t)(m0 + r) * 512 + (kb - 64) + cl * 8;
      __builtin_amdgcn_global_load_lds((gvoid*)src, (svoid*)&As[g * 512], 16, 0, 0);
    }
#pragma unroll
    for (int s = 0; s < 4; ++s) {
      const int g = wv * 4 + s;
      if (g < 14 && g != 8 && g != 9) {
        const int r = g * 8 + g8;
        const bf16* src = BT + (size_t)(n0 + r) * KA + kb + cl * 8;
        __builtin_amdgcn_global_load_lds((gvoid*)src, (svoid*)&Bs[g * 512], 16, 0, 0);
      }
    }
    __syncthreads();
#pragma unroll
    for (int s = 0; s < 2; ++s) {
      const int lc = s * 4 + quad;
      bf16x8 afr[TM];
      bf16x8 bfr[6];
#pragma unroll
      for (int i = 0; i < TM; ++i) {
        const int r = wv * 32 + i * 16 + lr;
        afr[i] = *reinterpret_cast<const bf16x8*>(&As[r * 64 + ((lc ^ (r & 7)) << 3)]);
      }
#pragma unroll
      for (int jj = 0; jj < 6; ++jj) {
        const int r = JMAP[jj] * 16 + lr;
        bfr[jj] = *reinterpret_cast<const bf16x8*>(&Bs[r * 64 + ((lc ^ (r & 7)) << 3)]);
      }
#pragma unroll
      for (int i = 0; i < TM; ++i)
#pragma unroll
        for (int jj = 0; jj < 6; ++jj)
          acc[i][JMAP[jj]] =
              __builtin_amdgcn_mfma_f32_16x16x32_bf16(afr[i], bfr[jj], acc[i][JMAP[jj]], 0, 0, 0);
    }
  }

  // ---- fused gate epilogue: all roles in-lane (fast-math) ----
  const int hcol = n_idx * 16 + lr;
  const float bvi = bvec[hcol], bvf = bvec[512 + hcol];
  const float bvo = bvec[1024 + hcol], bvc = bvec[1536 + hcol];
  const float wtt = WtT[hcol], bt_ = bT[hcol];
#pragma unroll
  for (int i = 0; i < TM; ++i) {
#pragma unroll
    for (int r = 0; r < 4; ++r) {
      const int m = m0 + wv * 32 + i * 16 + quad * 4 + r;
      const float td = tdT[m];
      const size_t o = (size_t)m * 512 + hcol;
      const float c_old = cbuf[o];
      const float i_ = fsigm2(acc[i][0][r] + bvi);
      const float f_ = fsigm2(acc[i][1][r] + bvf);
      const float o_ = fsigm2(acc[i][2][r] + bvo);
      const float ch = ftanh2(acc[i][3][r] + bvc);
      const float tg = fsigm2(acc[i][4][r] + fsigm2(td * wtt) + bt_);
      const float cn = f_ * c_old + (i_ + tg) * ch;
      cbuf[o] = cn;
      hcur[o] = (bf16)(o_ * ftanh2(cn));
      waSlot[o] = (bf16)acc[i][5][r];
      weSlot[o] = (bf16)acc[i][6][r];
    }
  }
}

// ---------------------------------------------------------------------------
// GEMM2: hcur[4096x512] @ wbwgT^T -> hWbG bf16 [4096x1024] (+baPad).
// BM=128, BN=64, BK=64, 256 threads (4 waves in m), 512 blocks = 2/CU. (R1 win)
// ---------------------------------------------------------------------------
__global__ __launch_bounds__(256, 4)
void gemm2_kernel(const bf16* __restrict__ hcur, const bf16* __restrict__ wbwgT,
                  const float* __restrict__ baPad, bf16* __restrict__ hWbG) {
  __shared__ __align__(16) bf16 As[128 * 64];  // 16 KB
  __shared__ __align__(16) bf16 Bs[64 * 64];   // 8 KB

  const int tid = threadIdx.x;
  const int lane = tid & 63;
  const int wv = tid >> 6;   // 0..3, m-stripe of 32 rows
  const int quad = lane >> 4;
  const int lr = lane & 15;
  const int bid = blockIdx.x;
  const int m0 = (bid >> 4) * 128;
  const int n0 = (bid & 15) * 64;
  const int g8 = lane >> 3;
  const int cl = (lane & 7) ^ g8;

  floatx4 acc[2][4];
#pragma unroll
  for (int i = 0; i < 2; ++i)
#pragma unroll
    for (int j = 0; j < 4; ++j) {
      acc[i][j][0] = 0.f; acc[i][j][1] = 0.f; acc[i][j][2] = 0.f; acc[i][j][3] = 0.f;
    }

  for (int kt = 0; kt < 8; ++kt) {
    const int kb = kt * 64;
    __syncthreads();
#pragma unroll
    for (int s = 0; s < 4; ++s) {  // A: 16 groups of 8 rows, 4 per wave
      const int g = wv * 4 + s;
      const int r = g * 8 + g8;
      const bf16* src = hcur + (size_t)(m0 + r) * 512 + kb + cl * 8;
      __builtin_amdgcn_global_load_lds((gvoid*)src, (svoid*)&As[g * 512], 16, 0, 0);
    }
#pragma unroll
    for (int s = 0; s < 2; ++s) {  // B: 8 groups of 8 rows, 2 per wave
      const int g = wv * 2 + s;
      const int r = g * 8 + g8;
      const bf16* src = wbwgT + (size_t)(n0 + r) * 512 + kb + cl * 8;
      __builtin_amdgcn_global_load_lds((gvoid*)src, (svoid*)&Bs[g * 512], 16, 0, 0);
    }
    __syncthreads();
#pragma unroll
    for (int s = 0; s < 2; ++s) {
      const int lc = s * 4 + quad;
      bf16x8 afr[2];
      bf16x8 bfr[4];
#pragma unroll
      for (int i = 0; i < 2; ++i) {
        const int r = wv * 32 + i * 16 + lr;
        afr[i] = *reinterpret_cast<const bf16x8*>(&As[r * 64 + ((lc ^ (r & 7)) << 3)]);
      }
#pragma unroll
      for (int j = 0; j < 4; ++j) {
        const int r = j * 16 + lr;
        bfr[j] = *reinterpret_cast<const bf16x8*>(&Bs[r * 64 + ((lc ^ (r & 7)) << 3)]);
      }
#pragma unroll
      for (int i = 0; i < 2; ++i)
#pragma unroll
        for (int j = 0; j < 4; ++j)
          acc[i][j] = __builtin_amdgcn_mfma_f32_16x16x32_bf16(afr[i], bfr[j], acc[i][j], 0, 0, 0);
    }
  }

#pragma unroll
  for (int i = 0; i < 2; ++i) {
#pragma unroll
    for (int j = 0; j < 4; ++j) {
      const int n = n0 + j * 16 + lr;
      const float bb = baPad[n];
#pragma unroll
      for (int r = 0; r < 4; ++r) {
        const int m = m0 + wv * 32 + i * 16 + quad * 4 + r;
        hWbG[(size_t)m * 1024 + n] = (bf16)(acc[i][j][r] + bb);
      }
    }
  }
}

// ---------------------------------------------------------------------------
// Generic MFMA GEMM (glds staging, BK=32 swizzle) — head only.
// mode 3: relu(v+cBias2) -> bf16 outBa
// ---------------------------------------------------------------------------
template <int BM, int BN>
__global__ __launch_bounds__(256)
void gemm_glds_kernel(const bf16* __restrict__ A1, int ld1, int K1,
                      const bf16* __restrict__ A2, int ld2,
                      const bf16* __restrict__ BT, int K, int mode,
                      float* __restrict__ outF, int ldF, const float* __restrict__ colBias,
                      bf16* __restrict__ outBa, int ldBa, const float* __restrict__ cBias2) {
  constexpr int BK = 32;
  constexpr int WM = BM / 2;
  constexpr int WN = BN / 2;
  constexpr int TM = WM / 16;
  constexpr int TN = WN / 16;
  constexpr int AIW = BM / 64;
  constexpr int BIW = BN / 64;
  __shared__ __align__(16) bf16 As[BM * BK];
  __shared__ __align__(16) bf16 Bs[BN * BK];

  const int tid = threadIdx.x;
  const int lane = tid & 63;
  const int wv = tid >> 6;
  const int wy = wv >> 1;
  const int wx = wv & 1;
  const int quad = lane >> 4;
  const int lr = lane & 15;
  const int m0 = blockIdx.y * BM;
  const int n0 = blockIdx.x * BN;
  const int sw = quad ^ ((lr >> 1) & 3);
  const int srow = lane >> 2;
  const int cl = (lane & 3) ^ ((lane >> 3) & 3);

  floatx4 acc[TM][TN];
#pragma unroll
  for (int i = 0; i < TM; ++i)
#pragma unroll
    for (int j = 0; j < TN; ++j) {
      acc[i][j][0] = 0.f; acc[i][j][1] = 0.f; acc[i][j][2] = 0.f; acc[i][j][3] = 0.f;
    }

  const int kTiles = K / BK;
  for (int kt = 0; kt < kTiles; ++kt) {
    const int kb = kt * BK;
    __syncthreads();
#pragma unroll
    for (int s = 0; s < AIW; ++s) {
      const int rbase = (wv * AIW + s) * 16;
      const int r = rbase + srow;
      const int col = kb + cl * 8;
      const bf16* src = (col < K1) ? (A1 + (size_t)(m0 + r) * ld1 + col)
                                   : (A2 + (size_t)(m0 + r) * ld2 + (col - K1));
      __builtin_amdgcn_global_load_lds((gvoid*)src, (svoid*)&As[rbase * BK], 16, 0, 0);
    }
#pragma unroll
    for (int s = 0; s < BIW; ++s) {
      const int rbase = (wv * BIW + s) * 16;
      const int r = rbase + srow;
      const bf16* src = BT + (size_t)(n0 + r) * K + kb + cl * 8;
      __builtin_amdgcn_global_load_lds((gvoid*)src, (svoid*)&Bs[rbase * BK], 16, 0, 0);
    }
    __syncthreads();
    bf16x8 afr[TM];
    bf16x8 bfr[TN];
#pragma unroll
    for (int i = 0; i < TM; ++i)
      afr[i] = *reinterpret_cast<const bf16x8*>(&As[(wy * WM + i * 16 + lr) * BK + sw * 8]);
#pragma unroll
    for (int j = 0; j < TN; ++j)
      bfr[j] = *reinterpret_cast<const bf16x8*>(&Bs[(wx * WN + j * 16 + lr) * BK + sw * 8]);
#pragma unroll
    for (int i = 0; i < TM; ++i)
#pragma unroll
      for (int j = 0; j < TN; ++j)
        acc[i][j] = __builtin_amdgcn_mfma_f32_16x16x32_bf16(afr[i], bfr[j], acc[i][j], 0, 0, 0);
  }

#pragma unroll
  for (int i = 0; i < TM; ++i) {
#pragma unroll
    for (int j = 0; j < TN; ++j) {
#pragma unroll
      for (int r = 0; r < 4; ++r) {
        int m = m0 + wy * WM + i * 16 + quad * 4 + r;
        int n = n0 + wx * WN + j * 16 + lr;
        float v = acc[i][j][r];
        if (mode == 0) {
          if (colBias != nullptr) v += colBias[n];
          outF[(size_t)m * ldF + n] = v;
        } else {  // mode 3
          v += cBias2[n];
          v = v > 0.f ? v : 0.f;
          outBa[(size_t)m * ldBa + n] = (bf16)v;
        }
      }
    }
  }
}

// ---------------------------------------------------------------------------
// Setup kernels (run every call; ws re-poisoned by harness)
// ---------------------------------------------------------------------------
// Packed WcombT[n][k], n<3584: blk=n/112, role=(n%112)>>4, h=blk*16+(n&15)
__global__ void pack_wcombT_kernel(const float* __restrict__ Wx, const float* __restrict__ Uh,
                                   const float* __restrict__ Wt, const float* __restrict__ WxT,
                                   const float* __restrict__ Wa, const float* __restrict__ We,
                                   bf16* __restrict__ out) {
  int idx = blockIdx.x * 256 + threadIdx.x;
  if (idx >= NR * KA) return;
  int n = idx / KA;
  int k = idx - n * KA;
  int blk = n / 112;
  int rem = n - blk * 112;
  int role = rem >> 4;
  int h = blk * 16 + (rem & 15);
  float v = 0.f;
  if (k < 63) {
    if (role < 4) v = Wx[k * 2048 + role * 512 + h];
    else if (role == 4) v = WxT[k * 512 + h];
  } else if (k == 63) {
    if (role < 3) v = Wt[role * 512 + h];
  } else {
    int kh = k - 64;
    if (role < 4) v = Uh[kh * 2048 + role * 512 + h];
    else if (role == 5) v = Wa[kh * 512 + h];
    else if (role == 6) v = We[kh * 512 + h];
  }
  out[idx] = (bf16)v;
}

__global__ void pack_t_kernel(const float* __restrict__ in, bf16* __restrict__ out, int N, int K) {
  int idx = blockIdx.x * 256 + threadIdx.x;
  if (idx >= N * K) return;
  int n = idx / K;
  int j = idx - n * K;
  out[idx] = (bf16)in[(size_t)j * N + n];
}

__global__ __launch_bounds__(512)
void setup_misc_kernel(const float* __restrict__ init_proj, const float* __restrict__ Wa,
                       const float* __restrict__ We, const float* __restrict__ ba,
                       float* __restrict__ sWa, float* __restrict__ sWe,
                       float* __restrict__ baPad) {
  __shared__ float s_sh[HDIM];
  int h = threadIdx.x;
  float acc = 0.f;
  for (int f = 0; f < 64; ++f) acc += init_proj[f * HDIM + h];
  s_sh[h] = acc;
  baPad[h] = ba[h];
  baPad[HDIM + h] = 0.f;
  __syncthreads();
  float a2 = 0.f, a3 = 0.f;
  for (int i = 0; i < HDIM; ++i) {
    a2 += s_sh[i] * Wa[i * HDIM + h];
    a3 += s_sh[i] * We[i * HDIM + h];
  }
  sWa[h] = a2;
  sWe[h] = a3;
}

__global__ void zero_state_kernel(float* __restrict__ c, bf16* __restrict__ h) {
  int idx = blockIdx.x * 256 + threadIdx.x;
  if (idx >= BATCH * HDIM) return;
  c[idx] = 0.f;
  h[idx] = (bf16)0.f;
}

__global__ void build_x_kernel(const float* __restrict__ inputs, bf16* __restrict__ xbuf,
                               float* __restrict__ tdT) {
  int idx = blockIdx.x * 256 + threadIdx.x;
  if (idx >= TSTEPS * BATCH * 64) return;
  int c = idx & 63;
  int bt = idx >> 6;
  int t = bt >> 12;
  int b = bt & 4095;
  float v;
  if (c < 63) {
    v = inputs[(size_t)b * 1024 + t * 64 + 1 + c];
  } else {
    v = inputs[(size_t)b * 1024 + t * 64];
    tdT[t * BATCH + b] = v;
  }
  xbuf[idx] = (bf16)v;
}

// ---------------------------------------------------------------------------
// Attention + h_new epilogue — R8 two-pass chunked pipeline (R13 measured
// 986.96, best). R16 delta: CH 4->6 (per-burst MLP 4->6, fences/pass 4->3)
// and w[] array eliminated (pass 2 recomputes aj=exp2(q[j]-mx)*inv from the
// live q[]; identical values, -15 VGPR). R12 online-softmax and R15
// wave-pair split both regressed — this two-pass shape is the local optimum.
// ---------------------------------------------------------------------------
template <int K>
__global__ __launch_bounds__(256, 4)
void attention_kernel(const bf16* __restrict__ hWbG,
                      const float* __restrict__ sWa, const float* __restrict__ sWe,
                      const float* __restrict__ va, const float* __restrict__ bh,
                      const bf16* __restrict__ histWa, const bf16* __restrict__ histWe,
                      bf16* __restrict__ hbuf) {
  constexpr float C = 2.8853900817779268f;   // 2*log2(e)
  constexpr float L2E = 1.4426950408889634f; // log2(e)
  constexpr int CH = 6;
  constexpr int NC = (K + CH - 1) / CH;      // chunks (0 when K==0)
  const int b = blockIdx.x * 4 + (threadIdx.x >> 6);
  const int lane = threadIdx.x & 63;
  const bf16* wbp = hWbG + (size_t)b * 1024 + lane * 8;
  bf16x8 wbv = *reinterpret_cast<const bf16x8*>(wbp);
  bf16x8 wgv = *reinterpret_cast<const bf16x8*>(wbp + 512);

  const bf16* pa = histWa + (size_t)b * HDIM + lane * 8;  // + j*BATCH*HDIM per row
  const bf16* pe = histWe + (size_t)b * HDIM + lane * 8;
  constexpr size_t RSTR = (size_t)BATCH * HDIM;

  bf16x8 stg[2][CH];
  // prologue: issue chunk 0 of histWa
  if (NC > 0) {
#pragma unroll
    for (int r = 0; r < CH; ++r)
      if (r < K) stg[0][r] = *reinterpret_cast<const bf16x8*>(pa + (size_t)r * RSTR);
    asm volatile("" ::: "memory");
  }

  float wb2[8], vv[8];
  float svv = 0.f;
#pragma unroll
  for (int i = 0; i < 8; ++i) {
    wb2[i] = (float)wbv[i] * C;
    vv[i] = va[lane * 8 + i];
    svv += vv[i];
  }

  // e_init (only when K < 15) — computed under chunk-0 load latency
  float e_init = 0.f;
  if (K < 15) {
    float p = 0.f;
#pragma unroll
    for (int i = 0; i < 8; ++i) {
      float r = __builtin_amdgcn_rcpf(exp2f(fmaf(sWa[lane * 8 + i], C, wb2[i])) + 1.f);
      p = fmaf(vv[i], r, p);
    }
    e_init = waveAllSum(fmaf(-2.f, p, svv));
  }

  // ---- pass 1 pipelined: issue chunk c+1, compute q for chunk c ----
  float q[K > 0 ? K : 1];
#pragma unroll
  for (int c = 0; c < NC; ++c) {
    if (c + 1 < NC) {
#pragma unroll
      for (int r = 0; r < CH; ++r) {
        const int j = (c + 1) * CH + r;
        if (j < K)
          stg[(c + 1) & 1][r] = *reinterpret_cast<const bf16x8*>(pa + (size_t)j * RSTR);
      }
      asm volatile("" ::: "memory");
    }
#pragma unroll
    for (int r = 0; r < CH; ++r) {
      const int j = c * CH + r;
      if (j < K) {
        float p = 0.f;
#pragma unroll
        for (int i = 0; i < 8; ++i) {
          float t = __builtin_amdgcn_rcpf(
              exp2f(fmaf((float)stg[c & 1][r][i], C, wb2[i])) + 1.f);
          p = fmaf(vv[i], t, p);
        }
        q[j] = fmaf(-2.f, p, svv);
      }
    }
  }

  // ---- issue hve chunk 0 now; butterfly + softmax cover its latency ----
  bf16x8 ebuf[2][CH];
  if (NC > 0) {
#pragma unroll
    for (int r = 0; r < CH; ++r)
      if (r < K) ebuf[0][r] = *reinterpret_cast<const bf16x8*>(pe + (size_t)r * RSTR);
    asm volatile("" ::: "memory");
  }

  // joint butterfly over all j (cross-j ILP)
#pragma unroll
  for (int off = 32; off > 0; off >>= 1) {
#pragma unroll
    for (int j = 0; j < K; ++j) q[j] += __shfl_xor(q[j], off, 64);
  }

  // ---- softmax over {init x (15-K), q[0..K)} ----
  float mx = (K < 15) ? e_init : -1e30f;
#pragma unroll
  for (int j = 0; j < K; ++j) mx = fmaxf(mx, q[j]);
  float winit = (K < 15) ? (float)(15 - K) * exp2f((e_init - mx) * L2E) : 0.f;
  float denom = winit;
#pragma unroll
  for (int j = 0; j < K; ++j) denom += exp2f((q[j] - mx) * L2E);
  const float inv = __builtin_amdgcn_rcpf(denom);

  // ---- pass 2 pipelined: issue hve chunk c+1, accumulate chunk c ----
  float cx[8];
  const float ai = winit * inv;
#pragma unroll
  for (int i = 0; i < 8; ++i) cx[i] = ai * sWe[lane * 8 + i];
#pragma unroll
  for (int c = 0; c < NC; ++c) {
    if (c + 1 < NC) {
#pragma unroll
      for (int r = 0; r < CH; ++r) {
        const int j = (c + 1) * CH + r;
        if (j < K)
          ebuf[(c + 1) & 1][r] = *reinterpret_cast<const bf16x8*>(pe + (size_t)j * RSTR);
      }
      asm volatile("" ::: "memory");
    }
#pragma unroll
    for (int r = 0; r < CH; ++r) {
      const int j = c * CH + r;
      if (j < K) {
        const float aj = exp2f((q[j] - mx) * L2E) * inv;
#pragma unroll
        for (int i = 0; i < 8; ++i) cx[i] = fmaf(aj, (float)ebuf[c & 1][r][i], cx[i]);
      }
    }
  }

  bf16x8 hnew;
#pragma unroll
  for (int i = 0; i < 8; ++i) {
    float s = cx[i] + (float)wgv[i] + bh[lane * 8 + i];
    float r = __builtin_amdgcn_rcpf(exp2f(s * C) + 1.f);
    hnew[i] = (bf16)fmaf(-2.f, r, 1.f);
  }
  *reinterpret_cast<bf16x8*>(hbuf + (size_t)b * HDIM + lane * 8) = hnew;
}

__global__ __launch_bounds__(256)
void head_kernel(const bf16* __restrict__ hd1, const float* __restrict__ W2,
                 const float* __restrict__ b2, const float* __restrict__ W3,
                 const float* __restrict__ b3, float* __restrict__ out) {
  __shared__ float W2s[256 * 32];
  __shared__ float b2s[32];
  __shared__ float W3s[64];
  __shared__ float b3s[2];
  for (int i = threadIdx.x; i < 256 * 32; i += 256) W2s[i] = W2[i];
  if (threadIdx.x < 32) b2s[threadIdx.x] = b2[threadIdx.x];
  if (threadIdx.x < 64) W3s[threadIdx.x] = W3[threadIdx.x];
  if (threadIdx.x < 2) b3s[threadIdx.x] = b3[threadIdx.x];
  __syncthreads();
  int row = blockIdx.x * 256 + threadIdx.x;
  float acc[32];
#pragma unroll
  for (int j = 0; j < 32; ++j) acc[j] = b2s[j];
  const bf16* hp = hd1 + (size_t)row * 256;
  for (int i = 0; i < 256; ++i) {
    float hv = (float)hp[i];
#pragma unroll
    for (int j = 0; j < 32; ++j) acc[j] += hv * W2s[i * 32 + j];
  }
  float l0 = b3s[0], l1 = b3s[1];
#pragma unroll
  for (int j = 0; j < 32; ++j) {
    float r = fmaxf(acc[j], 0.f);
    l0 += r * W3s[j * 2];
    l1 += r * W3s[j * 2 + 1];
  }
  float m = fmaxf(l0, l1);
  float e0 = __expf(l0 - m), e1 = __expf(l1 - m);
  float inv = 1.f / (e0 + e1);
  out[(size_t)row * 2] = e0 * inv;
  out[(size_t)row * 2 + 1] = e1 * inv;
}

// ---------------------------------------------------------------------------
extern "C" void kernel_launch(void* const* d_in, const int* in_sizes, int n_in,
                              void* d_out, int out_size, void* d_ws, size_t ws_size,
                              hipStream_t stream) {
  const float* inputs    = (const float*)d_in[0];
  const float* init_proj = (const float*)d_in[1];
  const float* Wx  = (const float*)d_in[3];
  const float* Uh  = (const float*)d_in[4];
  const float* Wt  = (const float*)d_in[5];
  const float* bv  = (const float*)d_in[6];
  const float* WxT = (const float*)d_in[7];
  const float* WtT = (const float*)d_in[8];
  const float* bT  = (const float*)d_in[9];
  const float* Wa  = (const float*)d_in[10];
  const float* Wb  = (const float*)d_in[11];
  const float* va  = (const float*)d_in[12];
  const float* ba  = (const float*)d_in[13];
  const float* We  = (const float*)d_in[14];
  const float* Wg  = (const float*)d_in[15];
  const float* bh  = (const float*)d_in[16];
  const float* W1  = (const float*)d_in[17];
  const float* b1  = (const float*)d_in[18];
  const float* W2  = (const float*)d_in[19];
  const float* b2  = (const float*)d_in[20];
  const float* W3  = (const float*)d_in[21];
  const float* b3  = (const float*)d_in[22];
  float* out = (float*)d_out;

  char* wp = (char*)d_ws;
  auto carve = [&](size_t bytes) -> void* {
    void* p = (void*)wp;
    wp += (bytes + 255) & ~(size_t)255;
    return p;
  };
  bf16* wcombT = (bf16*)carve((size_t)NR * KA * 2);
  bf16* wbwgT  = (bf16*)carve((size_t)1024 * 512 * 2);
  bf16* w1T    = (bf16*)carve((size_t)256 * 512 * 2);
  float* sWa   = (float*)carve(512 * 4);
  float* sWe   = (float*)carve(512 * 4);
  float* baPad = (float*)carve(1024 * 4);
  bf16* xbuf   = (bf16*)carve((size_t)TSTEPS * BATCH * 64 * 2);
  float* tdT   = (float*)carve((size_t)TSTEPS * BATCH * 4);
  float* cbuf  = (float*)carve((size_t)BATCH * HDIM * 4);
  bf16* hbuf   = (bf16*)carve((size_t)BATCH * HDIM * 2);
  bf16* hcur   = (bf16*)carve((size_t)BATCH * HDIM * 2);
  bf16* hWbG   = (bf16*)carve((size_t)BATCH * 1024 * 2);
  bf16* histWa = (bf16*)carve((size_t)16 * BATCH * HDIM * 2);
  bf16* histWe = (bf16*)carve((size_t)16 * BATCH * HDIM * 2);
  bf16* hd1    = (bf16*)carve((size_t)BATCH * 256 * 2);

  // ---- setup ----
  build_x_kernel<<<(TSTEPS * BATCH * 64) / 256, 256, 0, stream>>>(inputs, xbuf, tdT);
  pack_wcombT_kernel<<<(NR * KA + 255) / 256, 256, 0, stream>>>(Wx, Uh, Wt, WxT, Wa, We, wcombT);
  pack_t_kernel<<<(512 * 512) / 256, 256, 0, stream>>>(Wb, wbwgT, 512, 512);
  pack_t_kernel<<<(512 * 512) / 256, 256, 0, stream>>>(Wg, wbwgT + (size_t)512 * 512, 512, 512);
  pack_t_kernel<<<(256 * 512) / 256, 256, 0, stream>>>(W1, w1T, 256, 512);
  setup_misc_kernel<<<1, 512, 0, stream>>>(init_proj, Wa, We, ba, sWa, sWe, baPad);
  zero_state_kernel<<<(BATCH * HDIM) / 256, 256, 0, stream>>>(cbuf, hbuf);

  // ---- recurrence: 3 kernels per step ----
#define ATTN_LAUNCH(KK)                                                              \
  case KK:                                                                           \
    attention_kernel<KK><<<BATCH / 4, 256, 0, stream>>>(hWbG, sWa, sWe, va, bh,      \
                                                        histWa, histWe, hbuf);       \
    break;

  for (int t = 0; t < TSTEPS; ++t) {
    bf16* waSlot = histWa + (size_t)((t + 15) & 15) * BATCH * HDIM;
    bf16* weSlot = histWe + (size_t)((t + 15) & 15) * BATCH * HDIM;
    gemm1_fused<<<1024, 256, 0, stream>>>(
        xbuf + (size_t)t * BATCH * 64, hbuf, wcombT, tdT + (size_t)t * BATCH, bv, WtT, bT,
        cbuf, hcur, waSlot, weSlot);
    gemm2_kernel<<<512, 256, 0, stream>>>(hcur, wbwgT, baPad, hWbG);
    switch (t) {
      ATTN_LAUNCH(0) ATTN_LAUNCH(1) ATTN_LAUNCH(2) ATTN_LAUNCH(3)
      ATTN_LAUNCH(4) ATTN_LAUNCH(5) ATTN_LAUNCH(6) ATTN_LAUNCH(7)
      ATTN_LAUNCH(8) ATTN_LAUNCH(9) ATTN_LAUNCH(10) ATTN_LAUNCH(11)
      ATTN_LAUNCH(12) ATTN_LAUNCH(13) ATTN_LAUNCH(14) ATTN_LAUNCH(15)
    }
  }
#undef ATTN_LAUNCH

  // ---- head ----
  gemm_glds_kernel<64, 128><<<dim3(256 / 128, BATCH / 64), 256, 0, stream>>>(
      hbuf, 512, 512, hbuf, 512, w1T, 512, 3, nullptr, 0, nullptr, hd1, 256, b1);
  head_kernel<<<BATCH / 256, 256, 0, stream>>>(hd1, W2, b2, W3, b3, out);
}

// Round 18
// 953.301 us; speedup vs baseline: 1.0909x; 1.0205x over previous
//
#include <hip/hip_runtime.h>
#include <hip/hip_bf16.h>

typedef __bf16 bf16;
typedef __attribute__((ext_vector_type(8))) __bf16 bf16x8;
typedef __attribute__((ext_vector_type(4))) float floatx4;

#define HDIM 512
#define BATCH 4096
#define TSTEPS 16
#define KA 576      // A width: 63 x-feats + td + 512 h
#define NR 3584     // GEMM1 out cols: 7 roles x 512 h (no pad role)

typedef const __attribute__((address_space(1))) void gvoid;
typedef __attribute__((address_space(3))) void svoid;

// Fast-math forms (validated R7 on attention, R13 on gemm1): single
// v_exp_f32 + v_rcp_f32, no IEEE division chains.
__device__ __forceinline__ float ftanh2(float x) {
  return fmaf(-2.f, __builtin_amdgcn_rcpf(exp2f(x * 2.8853900817779268f) + 1.f), 1.f);
}
__device__ __forceinline__ float fsigm2(float x) {
  return __builtin_amdgcn_rcpf(1.f + exp2f(-x * 1.4426950408889634f));
}

__device__ __forceinline__ float waveAllSum(float v) {
#pragma unroll
  for (int off = 32; off > 0; off >>= 1) v += __shfl_xor(v, off, 64);
  return v;
}

// ---------------------------------------------------------------------------
// Fused GEMM1 + gates. A = [x_t(63) | td | h(512)], B = role-interleaved WcombT
// with NO pad role: packed col n -> blk=n/112, role=(n%112)>>4, h=blk*16+(n&15).
// R17 retile: BM=256, BN=112, BK=64, TM=4 (waves 1x4 in m, WM=64).
// Rationale: B-tile re-staged by 4096/BM m-blocks -> halving that traffic
// (132->66 MB) and raising MFMA:ds_read from 24:16 to 48:20 per wave/K-tile.
// Grid 512 blocks = 2 blocks/CU (the R1-proven minimum for barrier overlap).
// VGPR ~180 -> __launch_bounds__(256,2); LDS 46 KB x 2 = 92 KB/CU.
// ROLE SPARSITY: kt==0 peeled (roles 0..4); kt>=1 roles {0,1,2,3,5,6}.
// Roles: 0..3 = zi,zf,zo,zc (td*Wt folded via A col63), 4 = tg, 5 = hWa, 6 = hWe.
// ---------------------------------------------------------------------------
__global__ __launch_bounds__(256, 2)
void gemm1_fused(const bf16* __restrict__ A1, const bf16* __restrict__ A2,
                 const bf16* __restrict__ BT,
                 const float* __restrict__ tdT, const float* __restrict__ bvec,
                 const float* __restrict__ WtT, const float* __restrict__ bT,
                 float* __restrict__ cbuf, bf16* __restrict__ hcur,
                 bf16* __restrict__ waSlot, bf16* __restrict__ weSlot) {
  constexpr int BM = 256, BN = 112, BK = 64;
  constexpr int TM = 4, TN = 7;
  __shared__ __align__(16) bf16 As[BM * BK];  // 32 KB
  __shared__ __align__(16) bf16 Bs[BN * BK];  // 14 KB

  const int tid = threadIdx.x;
  const int lane = tid & 63;
  const int wv = tid >> 6;     // m-quadrant (WM=64 each)
  const int quad = lane >> 4;
  const int lr = lane & 15;
  const int bid = blockIdx.x;
  const int xcd = bid & 7;
  const int p = bid >> 3;                   // [0,64)
  const int n_idx = (xcd << 2) | (p >> 4);  // [0,32): h-group
  const int m_idx = p & 15;                 // [0,16)
  const int m0 = m_idx * BM;
  const int n0 = n_idx * BN;
  const int g8 = lane >> 3;
  const int cl = (lane & 7) ^ g8;  // logical chunk fetched (phys = lc ^ (row&7))

  floatx4 acc[TM][TN];
#pragma unroll
  for (int i = 0; i < TM; ++i)
#pragma unroll
    for (int j = 0; j < TN; ++j) {
      acc[i][j][0] = 0.f; acc[i][j][1] = 0.f; acc[i][j][2] = 0.f; acc[i][j][3] = 0.f;
    }

  // ---- kt == 0 (x-part, A1): roles 0..4 only; B-groups 0..9 ----
  {
#pragma unroll
    for (int s = 0; s < 8; ++s) {  // A: 32 groups of 8 rows, 8 per wave
      const int g = wv * 8 + s;
      const int r = g * 8 + g8;
      const bf16* src = A1 + (size_t)(m0 + r) * 64 + cl * 8;
      __builtin_amdgcn_global_load_lds((gvoid*)src, (svoid*)&As[g * 512], 16, 0, 0);
    }
#pragma unroll
    for (int s = 0; s < 4; ++s) {  // B: groups 0..9 (roles 0..4)
      const int g = wv * 4 + s;
      if (g < 10) {
        const int r = g * 8 + g8;
        const bf16* src = BT + (size_t)(n0 + r) * KA + cl * 8;
        __builtin_amdgcn_global_load_lds((gvoid*)src, (svoid*)&Bs[g * 512], 16, 0, 0);
      }
    }
    __syncthreads();
#pragma unroll
    for (int s = 0; s < 2; ++s) {  // two K=32 half-steps
      const int lc = s * 4 + quad;
      bf16x8 afr[TM];
      bf16x8 bfr[5];
#pragma unroll
      for (int i = 0; i < TM; ++i) {
        const int r = wv * 64 + i * 16 + lr;
        afr[i] = *reinterpret_cast<const bf16x8*>(&As[r * 64 + ((lc ^ (r & 7)) << 3)]);
      }
#pragma unroll
      for (int j = 0; j < 5; ++j) {
        const int r = j * 16 + lr;
        bfr[j] = *reinterpret_cast<const bf16x8*>(&Bs[r * 64 + ((lc ^ (r & 7)) << 3)]);
      }
#pragma unroll
      for (int i = 0; i < TM; ++i)
#pragma unroll
        for (int j = 0; j < 5; ++j)
          acc[i][j] = __builtin_amdgcn_mfma_f32_16x16x32_bf16(afr[i], bfr[j], acc[i][j], 0, 0, 0);
    }
  }

  // ---- kt = 1..8 (h-part, A2): roles {0,1,2,3,5,6}; B-groups 0..7,10..13 ----
  constexpr int JMAP[6] = {0, 1, 2, 3, 5, 6};
  for (int kt = 1; kt < KA / BK; ++kt) {
    const int kb = kt * BK;
    __syncthreads();
#pragma unroll
    for (int s = 0; s < 8; ++s) {
      const int g = wv * 8 + s;
      const int r = g * 8 + g8;
      const bf16* src = A2 + (size_t)(m0 + r) * 512 + (kb - 64) + cl * 8;
      __builtin_amdgcn_global_load_lds((gvoid*)src, (svoid*)&As[g * 512], 16, 0, 0);
    }
#pragma unroll
    for (int s = 0; s < 4; ++s) {
      const int g = wv * 4 + s;
      if (g < 14 && g != 8 && g != 9) {
        const int r = g * 8 + g8;
        const bf16* src = BT + (size_t)(n0 + r) * KA + kb + cl * 8;
        __builtin_amdgcn_global_load_lds((gvoid*)src, (svoid*)&Bs[g * 512], 16, 0, 0);
      }
    }
    __syncthreads();
#pragma unroll
    for (int s = 0; s < 2; ++s) {
      const int lc = s * 4 + quad;
      bf16x8 afr[TM];
      bf16x8 bfr[6];
#pragma unroll
      for (int i = 0; i < TM; ++i) {
        const int r = wv * 64 + i * 16 + lr;
        afr[i] = *reinterpret_cast<const bf16x8*>(&As[r * 64 + ((lc ^ (r & 7)) << 3)]);
      }
#pragma unroll
      for (int jj = 0; jj < 6; ++jj) {
        const int r = JMAP[jj] * 16 + lr;
        bfr[jj] = *reinterpret_cast<const bf16x8*>(&Bs[r * 64 + ((lc ^ (r & 7)) << 3)]);
      }
#pragma unroll
      for (int i = 0; i < TM; ++i)
#pragma unroll
        for (int jj = 0; jj < 6; ++jj)
          acc[i][JMAP[jj]] =
              __builtin_amdgcn_mfma_f32_16x16x32_bf16(afr[i], bfr[jj], acc[i][JMAP[jj]], 0, 0, 0);
    }
  }

  // ---- fused gate epilogue: all roles in-lane (fast-math) ----
  const int hcol = n_idx * 16 + lr;
  const float bvi = bvec[hcol], bvf = bvec[512 + hcol];
  const float bvo = bvec[1024 + hcol], bvc = bvec[1536 + hcol];
  const float wtt = WtT[hcol], bt_ = bT[hcol];
#pragma unroll
  for (int i = 0; i < TM; ++i) {
#pragma unroll
    for (int r = 0; r < 4; ++r) {
      const int m = m0 + wv * 64 + i * 16 + quad * 4 + r;
      const float td = tdT[m];
      const size_t o = (size_t)m * 512 + hcol;
      const float c_old = cbuf[o];
      const float i_ = fsigm2(acc[i][0][r] + bvi);
      const float f_ = fsigm2(acc[i][1][r] + bvf);
      const float o_ = fsigm2(acc[i][2][r] + bvo);
      const float ch = ftanh2(acc[i][3][r] + bvc);
      const float tg = fsigm2(acc[i][4][r] + fsigm2(td * wtt) + bt_);
      const float cn = f_ * c_old + (i_ + tg) * ch;
      cbuf[o] = cn;
      hcur[o] = (bf16)(o_ * ftanh2(cn));
      waSlot[o] = (bf16)acc[i][5][r];
      weSlot[o] = (bf16)acc[i][6][r];
    }
  }
}

// ---------------------------------------------------------------------------
// GEMM2: hcur[4096x512] @ wbwgT^T -> hWbG bf16 [4096x1024] (+baPad).
// BM=128, BN=64, BK=64, 256 threads (4 waves in m), 512 blocks = 2/CU. (R1 win)
// ---------------------------------------------------------------------------
__global__ __launch_bounds__(256, 4)
void gemm2_kernel(const bf16* __restrict__ hcur, const bf16* __restrict__ wbwgT,
                  const float* __restrict__ baPad, bf16* __restrict__ hWbG) {
  __shared__ __align__(16) bf16 As[128 * 64];  // 16 KB
  __shared__ __align__(16) bf16 Bs[64 * 64];   // 8 KB

  const int tid = threadIdx.x;
  const int lane = tid & 63;
  const int wv = tid >> 6;   // 0..3, m-stripe of 32 rows
  const int quad = lane >> 4;
  const int lr = lane & 15;
  const int bid = blockIdx.x;
  const int m0 = (bid >> 4) * 128;
  const int n0 = (bid & 15) * 64;
  const int g8 = lane >> 3;
  const int cl = (lane & 7) ^ g8;

  floatx4 acc[2][4];
#pragma unroll
  for (int i = 0; i < 2; ++i)
#pragma unroll
    for (int j = 0; j < 4; ++j) {
      acc[i][j][0] = 0.f; acc[i][j][1] = 0.f; acc[i][j][2] = 0.f; acc[i][j][3] = 0.f;
    }

  for (int kt = 0; kt < 8; ++kt) {
    const int kb = kt * 64;
    __syncthreads();
#pragma unroll
    for (int s = 0; s < 4; ++s) {  // A: 16 groups of 8 rows, 4 per wave
      const int g = wv * 4 + s;
      const int r = g * 8 + g8;
      const bf16* src = hcur + (size_t)(m0 + r) * 512 + kb + cl * 8;
      __builtin_amdgcn_global_load_lds((gvoid*)src, (svoid*)&As[g * 512], 16, 0, 0);
    }
#pragma unroll
    for (int s = 0; s < 2; ++s) {  // B: 8 groups of 8 rows, 2 per wave
      const int g = wv * 2 + s;
      const int r = g * 8 + g8;
      const bf16* src = wbwgT + (size_t)(n0 + r) * 512 + kb + cl * 8;
      __builtin_amdgcn_global_load_lds((gvoid*)src, (svoid*)&Bs[g * 512], 16, 0, 0);
    }
    __syncthreads();
#pragma unroll
    for (int s = 0; s < 2; ++s) {
      const int lc = s * 4 + quad;
      bf16x8 afr[2];
      bf16x8 bfr[4];
#pragma unroll
      for (int i = 0; i < 2; ++i) {
        const int r = wv * 32 + i * 16 + lr;
        afr[i] = *reinterpret_cast<const bf16x8*>(&As[r * 64 + ((lc ^ (r & 7)) << 3)]);
      }
#pragma unroll
      for (int j = 0; j < 4; ++j) {
        const int r = j * 16 + lr;
        bfr[j] = *reinterpret_cast<const bf16x8*>(&Bs[r * 64 + ((lc ^ (r & 7)) << 3)]);
      }
#pragma unroll
      for (int i = 0; i < 2; ++i)
#pragma unroll
        for (int j = 0; j < 4; ++j)
          acc[i][j] = __builtin_amdgcn_mfma_f32_16x16x32_bf16(afr[i], bfr[j], acc[i][j], 0, 0, 0);
    }
  }

#pragma unroll
  for (int i = 0; i < 2; ++i) {
#pragma unroll
    for (int j = 0; j < 4; ++j) {
      const int n = n0 + j * 16 + lr;
      const float bb = baPad[n];
#pragma unroll
      for (int r = 0; r < 4; ++r) {
        const int m = m0 + wv * 32 + i * 16 + quad * 4 + r;
        hWbG[(size_t)m * 1024 + n] = (bf16)(acc[i][j][r] + bb);
      }
    }
  }
}

// ---------------------------------------------------------------------------
// Generic MFMA GEMM (glds staging, BK=32 swizzle) — head only.
// mode 3: relu(v+cBias2) -> bf16 outBa
// ---------------------------------------------------------------------------
template <int BM, int BN>
__global__ __launch_bounds__(256)
void gemm_glds_kernel(const bf16* __restrict__ A1, int ld1, int K1,
                      const bf16* __restrict__ A2, int ld2,
                      const bf16* __restrict__ BT, int K, int mode,
                      float* __restrict__ outF, int ldF, const float* __restrict__ colBias,
                      bf16* __restrict__ outBa, int ldBa, const float* __restrict__ cBias2) {
  constexpr int BK = 32;
  constexpr int WM = BM / 2;
  constexpr int WN = BN / 2;
  constexpr int TM = WM / 16;
  constexpr int TN = WN / 16;
  constexpr int AIW = BM / 64;
  constexpr int BIW = BN / 64;
  __shared__ __align__(16) bf16 As[BM * BK];
  __shared__ __align__(16) bf16 Bs[BN * BK];

  const int tid = threadIdx.x;
  const int lane = tid & 63;
  const int wv = tid >> 6;
  const int wy = wv >> 1;
  const int wx = wv & 1;
  const int quad = lane >> 4;
  const int lr = lane & 15;
  const int m0 = blockIdx.y * BM;
  const int n0 = blockIdx.x * BN;
  const int sw = quad ^ ((lr >> 1) & 3);
  const int srow = lane >> 2;
  const int cl = (lane & 3) ^ ((lane >> 3) & 3);

  floatx4 acc[TM][TN];
#pragma unroll
  for (int i = 0; i < TM; ++i)
#pragma unroll
    for (int j = 0; j < TN; ++j) {
      acc[i][j][0] = 0.f; acc[i][j][1] = 0.f; acc[i][j][2] = 0.f; acc[i][j][3] = 0.f;
    }

  const int kTiles = K / BK;
  for (int kt = 0; kt < kTiles; ++kt) {
    const int kb = kt * BK;
    __syncthreads();
#pragma unroll
    for (int s = 0; s < AIW; ++s) {
      const int rbase = (wv * AIW + s) * 16;
      const int r = rbase + srow;
      const int col = kb + cl * 8;
      const bf16* src = (col < K1) ? (A1 + (size_t)(m0 + r) * ld1 + col)
                                   : (A2 + (size_t)(m0 + r) * ld2 + (col - K1));
      __builtin_amdgcn_global_load_lds((gvoid*)src, (svoid*)&As[rbase * BK], 16, 0, 0);
    }
#pragma unroll
    for (int s = 0; s < BIW; ++s) {
      const int rbase = (wv * BIW + s) * 16;
      const int r = rbase + srow;
      const bf16* src = BT + (size_t)(n0 + r) * K + kb + cl * 8;
      __builtin_amdgcn_global_load_lds((gvoid*)src, (svoid*)&Bs[rbase * BK], 16, 0, 0);
    }
    __syncthreads();
    bf16x8 afr[TM];
    bf16x8 bfr[TN];
#pragma unroll
    for (int i = 0; i < TM; ++i)
      afr[i] = *reinterpret_cast<const bf16x8*>(&As[(wy * WM + i * 16 + lr) * BK + sw * 8]);
#pragma unroll
    for (int j = 0; j < TN; ++j)
      bfr[j] = *reinterpret_cast<const bf16x8*>(&Bs[(wx * WN + j * 16 + lr) * BK + sw * 8]);
#pragma unroll
    for (int i = 0; i < TM; ++i)
#pragma unroll
      for (int j = 0; j < TN; ++j)
        acc[i][j] = __builtin_amdgcn_mfma_f32_16x16x32_bf16(afr[i], bfr[j], acc[i][j], 0, 0, 0);
  }

#pragma unroll
  for (int i = 0; i < TM; ++i) {
#pragma unroll
    for (int j = 0; j < TN; ++j) {
#pragma unroll
      for (int r = 0; r < 4; ++r) {
        int m = m0 + wy * WM + i * 16 + quad * 4 + r;
        int n = n0 + wx * WN + j * 16 + lr;
        float v = acc[i][j][r];
        if (mode == 0) {
          if (colBias != nullptr) v += colBias[n];
          outF[(size_t)m * ldF + n] = v;
        } else {  // mode 3
          v += cBias2[n];
          v = v > 0.f ? v : 0.f;
          outBa[(size_t)m * ldBa + n] = (bf16)v;
        }
      }
    }
  }
}

// ---------------------------------------------------------------------------
// Setup kernels (run every call; ws re-poisoned by harness)
// ---------------------------------------------------------------------------
// Packed WcombT[n][k], n<3584: blk=n/112, role=(n%112)>>4, h=blk*16+(n&15)
__global__ void pack_wcombT_kernel(const float* __restrict__ Wx, const float* __restrict__ Uh,
                                   const float* __restrict__ Wt, const float* __restrict__ WxT,
                                   const float* __restrict__ Wa, const float* __restrict__ We,
                                   bf16* __restrict__ out) {
  int idx = blockIdx.x * 256 + threadIdx.x;
  if (idx >= NR * KA) return;
  int n = idx / KA;
  int k = idx - n * KA;
  int blk = n / 112;
  int rem = n - blk * 112;
  int role = rem >> 4;
  int h = blk * 16 + (rem & 15);
  float v = 0.f;
  if (k < 63) {
    if (role < 4) v = Wx[k * 2048 + role * 512 + h];
    else if (role == 4) v = WxT[k * 512 + h];
  } else if (k == 63) {
    if (role < 3) v = Wt[role * 512 + h];
  } else {
    int kh = k - 64;
    if (role < 4) v = Uh[kh * 2048 + role * 512 + h];
    else if (role == 5) v = Wa[kh * 512 + h];
    else if (role == 6) v = We[kh * 512 + h];
  }
  out[idx] = (bf16)v;
}

__global__ void pack_t_kernel(const float* __restrict__ in, bf16* __restrict__ out, int N, int K) {
  int idx = blockIdx.x * 256 + threadIdx.x;
  if (idx >= N * K) return;
  int n = idx / K;
  int j = idx - n * K;
  out[idx] = (bf16)in[(size_t)j * N + n];
}

__global__ __launch_bounds__(512)
void setup_misc_kernel(const float* __restrict__ init_proj, const float* __restrict__ Wa,
                       const float* __restrict__ We, const float* __restrict__ ba,
                       float* __restrict__ sWa, float* __restrict__ sWe,
                       float* __restrict__ baPad) {
  __shared__ float s_sh[HDIM];
  int h = threadIdx.x;
  float acc = 0.f;
  for (int f = 0; f < 64; ++f) acc += init_proj[f * HDIM + h];
  s_sh[h] = acc;
  baPad[h] = ba[h];
  baPad[HDIM + h] = 0.f;
  __syncthreads();
  float a2 = 0.f, a3 = 0.f;
  for (int i = 0; i < HDIM; ++i) {
    a2 += s_sh[i] * Wa[i * HDIM + h];
    a3 += s_sh[i] * We[i * HDIM + h];
  }
  sWa[h] = a2;
  sWe[h] = a3;
}

__global__ void zero_state_kernel(float* __restrict__ c, bf16* __restrict__ h) {
  int idx = blockIdx.x * 256 + threadIdx.x;
  if (idx >= BATCH * HDIM) return;
  c[idx] = 0.f;
  h[idx] = (bf16)0.f;
}

__global__ void build_x_kernel(const float* __restrict__ inputs, bf16* __restrict__ xbuf,
                               float* __restrict__ tdT) {
  int idx = blockIdx.x * 256 + threadIdx.x;
  if (idx >= TSTEPS * BATCH * 64) return;
  int c = idx & 63;
  int bt = idx >> 6;
  int t = bt >> 12;
  int b = bt & 4095;
  float v;
  if (c < 63) {
    v = inputs[(size_t)b * 1024 + t * 64 + 1 + c];
  } else {
    v = inputs[(size_t)b * 1024 + t * 64];
    tdT[t * BATCH + b] = v;
  }
  xbuf[idx] = (bf16)v;
}

// ---------------------------------------------------------------------------
// Attention + h_new epilogue — R16 measured-best shape (972.89): two-pass
// chunked pipeline, CH=6, w[] recomputed in pass 2. Unchanged this round.
// ---------------------------------------------------------------------------
template <int K>
__global__ __launch_bounds__(256, 4)
void attention_kernel(const bf16* __restrict__ hWbG,
                      const float* __restrict__ sWa, const float* __restrict__ sWe,
                      const float* __restrict__ va, const float* __restrict__ bh,
                      const bf16* __restrict__ histWa, const bf16* __restrict__ histWe,
                      bf16* __restrict__ hbuf) {
  constexpr float C = 2.8853900817779268f;   // 2*log2(e)
  constexpr float L2E = 1.4426950408889634f; // log2(e)
  constexpr int CH = 6;
  constexpr int NC = (K + CH - 1) / CH;      // chunks (0 when K==0)
  const int b = blockIdx.x * 4 + (threadIdx.x >> 6);
  const int lane = threadIdx.x & 63;
  const bf16* wbp = hWbG + (size_t)b * 1024 + lane * 8;
  bf16x8 wbv = *reinterpret_cast<const bf16x8*>(wbp);
  bf16x8 wgv = *reinterpret_cast<const bf16x8*>(wbp + 512);

  const bf16* pa = histWa + (size_t)b * HDIM + lane * 8;  // + j*BATCH*HDIM per row
  const bf16* pe = histWe + (size_t)b * HDIM + lane * 8;
  constexpr size_t RSTR = (size_t)BATCH * HDIM;

  bf16x8 stg[2][CH];
  // prologue: issue chunk 0 of histWa
  if (NC > 0) {
#pragma unroll
    for (int r = 0; r < CH; ++r)
      if (r < K) stg[0][r] = *reinterpret_cast<const bf16x8*>(pa + (size_t)r * RSTR);
    asm volatile("" ::: "memory");
  }

  float wb2[8], vv[8];
  float svv = 0.f;
#pragma unroll
  for (int i = 0; i < 8; ++i) {
    wb2[i] = (float)wbv[i] * C;
    vv[i] = va[lane * 8 + i];
    svv += vv[i];
  }

  // e_init (only when K < 15) — computed under chunk-0 load latency
  float e_init = 0.f;
  if (K < 15) {
    float p = 0.f;
#pragma unroll
    for (int i = 0; i < 8; ++i) {
      float r = __builtin_amdgcn_rcpf(exp2f(fmaf(sWa[lane * 8 + i], C, wb2[i])) + 1.f);
      p = fmaf(vv[i], r, p);
    }
    e_init = waveAllSum(fmaf(-2.f, p, svv));
  }

  // ---- pass 1 pipelined: issue chunk c+1, compute q for chunk c ----
  float q[K > 0 ? K : 1];
#pragma unroll
  for (int c = 0; c < NC; ++c) {
    if (c + 1 < NC) {
#pragma unroll
      for (int r = 0; r < CH; ++r) {
        const int j = (c + 1) * CH + r;
        if (j < K)
          stg[(c + 1) & 1][r] = *reinterpret_cast<const bf16x8*>(pa + (size_t)j * RSTR);
      }
      asm volatile("" ::: "memory");
    }
#pragma unroll
    for (int r = 0; r < CH; ++r) {
      const int j = c * CH + r;
      if (j < K) {
        float p = 0.f;
#pragma unroll
        for (int i = 0; i < 8; ++i) {
          float t = __builtin_amdgcn_rcpf(
              exp2f(fmaf((float)stg[c & 1][r][i], C, wb2[i])) + 1.f);
          p = fmaf(vv[i], t, p);
        }
        q[j] = fmaf(-2.f, p, svv);
      }
    }
  }

  // ---- issue hve chunk 0 now; butterfly + softmax cover its latency ----
  bf16x8 ebuf[2][CH];
  if (NC > 0) {
#pragma unroll
    for (int r = 0; r < CH; ++r)
      if (r < K) ebuf[0][r] = *reinterpret_cast<const bf16x8*>(pe + (size_t)r * RSTR);
    asm volatile("" ::: "memory");
  }

  // joint butterfly over all j (cross-j ILP)
#pragma unroll
  for (int off = 32; off > 0; off >>= 1) {
#pragma unroll
    for (int j = 0; j < K; ++j) q[j] += __shfl_xor(q[j], off, 64);
  }

  // ---- softmax over {init x (15-K), q[0..K)} ----
  float mx = (K < 15) ? e_init : -1e30f;
#pragma unroll
  for (int j = 0; j < K; ++j) mx = fmaxf(mx, q[j]);
  float winit = (K < 15) ? (float)(15 - K) * exp2f((e_init - mx) * L2E) : 0.f;
  float denom = winit;
#pragma unroll
  for (int j = 0; j < K; ++j) denom += exp2f((q[j] - mx) * L2E);
  const float inv = __builtin_amdgcn_rcpf(denom);

  // ---- pass 2 pipelined: issue hve chunk c+1, accumulate chunk c ----
  float cx[8];
  const float ai = winit * inv;
#pragma unroll
  for (int i = 0; i < 8; ++i) cx[i] = ai * sWe[lane * 8 + i];
#pragma unroll
  for (int c = 0; c < NC; ++c) {
    if (c + 1 < NC) {
#pragma unroll
      for (int r = 0; r < CH; ++r) {
        const int j = (c + 1) * CH + r;
        if (j < K)
          ebuf[(c + 1) & 1][r] = *reinterpret_cast<const bf16x8*>(pe + (size_t)j * RSTR);
      }
      asm volatile("" ::: "memory");
    }
#pragma unroll
    for (int r = 0; r < CH; ++r) {
      const int j = c * CH + r;
      if (j < K) {
        const float aj = exp2f((q[j] - mx) * L2E) * inv;
#pragma unroll
        for (int i = 0; i < 8; ++i) cx[i] = fmaf(aj, (float)ebuf[c & 1][r][i], cx[i]);
      }
    }
  }

  bf16x8 hnew;
#pragma unroll
  for (int i = 0; i < 8; ++i) {
    float s = cx[i] + (float)wgv[i] + bh[lane * 8 + i];
    float r = __builtin_amdgcn_rcpf(exp2f(s * C) + 1.f);
    hnew[i] = (bf16)fmaf(-2.f, r, 1.f);
  }
  *reinterpret_cast<bf16x8*>(hbuf + (size_t)b * HDIM + lane * 8) = hnew;
}

__global__ __launch_bounds__(256)
void head_kernel(const bf16* __restrict__ hd1, const float* __restrict__ W2,
                 const float* __restrict__ b2, const float* __restrict__ W3,
                 const float* __restrict__ b3, float* __restrict__ out) {
  __shared__ float W2s[256 * 32];
  __shared__ float b2s[32];
  __shared__ float W3s[64];
  __shared__ float b3s[2];
  for (int i = threadIdx.x; i < 256 * 32; i += 256) W2s[i] = W2[i];
  if (threadIdx.x < 32) b2s[threadIdx.x] = b2[threadIdx.x];
  if (threadIdx.x < 64) W3s[threadIdx.x] = W3[threadIdx.x];
  if (threadIdx.x < 2) b3s[threadIdx.x] = b3[threadIdx.x];
  __syncthreads();
  int row = blockIdx.x * 256 + threadIdx.x;
  float acc[32];
#pragma unroll
  for (int j = 0; j < 32; ++j) acc[j] = b2s[j];
  const bf16* hp = hd1 + (size_t)row * 256;
  for (int i = 0; i < 256; ++i) {
    float hv = (float)hp[i];
#pragma unroll
    for (int j = 0; j < 32; ++j) acc[j] += hv * W2s[i * 32 + j];
  }
  float l0 = b3s[0], l1 = b3s[1];
#pragma unroll
  for (int j = 0; j < 32; ++j) {
    float r = fmaxf(acc[j], 0.f);
    l0 += r * W3s[j * 2];
    l1 += r * W3s[j * 2 + 1];
  }
  float m = fmaxf(l0, l1);
  float e0 = __expf(l0 - m), e1 = __expf(l1 - m);
  float inv = 1.f / (e0 + e1);
  out[(size_t)row * 2] = e0 * inv;
  out[(size_t)row * 2 + 1] = e1 * inv;
}

// ---------------------------------------------------------------------------
extern "C" void kernel_launch(void* const* d_in, const int* in_sizes, int n_in,
                              void* d_out, int out_size, void* d_ws, size_t ws_size,
                              hipStream_t stream) {
  const float* inputs    = (const float*)d_in[0];
  const float* init_proj = (const float*)d_in[1];
  const float* Wx  = (const float*)d_in[3];
  const float* Uh  = (const float*)d_in[4];
  const float* Wt  = (const float*)d_in[5];
  const float* bv  = (const float*)d_in[6];
  const float* WxT = (const float*)d_in[7];
  const float* WtT = (const float*)d_in[8];
  const float* bT  = (const float*)d_in[9];
  const float* Wa  = (const float*)d_in[10];
  const float* Wb  = (const float*)d_in[11];
  const float* va  = (const float*)d_in[12];
  const float* ba  = (const float*)d_in[13];
  const float* We  = (const float*)d_in[14];
  const float* Wg  = (const float*)d_in[15];
  const float* bh  = (const float*)d_in[16];
  const float* W1  = (const float*)d_in[17];
  const float* b1  = (const float*)d_in[18];
  const float* W2  = (const float*)d_in[19];
  const float* b2  = (const float*)d_in[20];
  const float* W3  = (const float*)d_in[21];
  const float* b3  = (const float*)d_in[22];
  float* out = (float*)d_out;

  char* wp = (char*)d_ws;
  auto carve = [&](size_t bytes) -> void* {
    void* p = (void*)wp;
    wp += (bytes + 255) & ~(size_t)255;
    return p;
  };
  bf16* wcombT = (bf16*)carve((size_t)NR * KA * 2);
  bf16* wbwgT  = (bf16*)carve((size_t)1024 * 512 * 2);
  bf16* w1T    = (bf16*)carve((size_t)256 * 512 * 2);
  float* sWa   = (float*)carve(512 * 4);
  float* sWe   = (float*)carve(512 * 4);
  float* baPad = (float*)carve(1024 * 4);
  bf16* xbuf   = (bf16*)carve((size_t)TSTEPS * BATCH * 64 * 2);
  float* tdT   = (float*)carve((size_t)TSTEPS * BATCH * 4);
  float* cbuf  = (float*)carve((size_t)BATCH * HDIM * 4);
  bf16* hbuf   = (bf16*)carve((size_t)BATCH * HDIM * 2);
  bf16* hcur   = (bf16*)carve((size_t)BATCH * HDIM * 2);
  bf16* hWbG   = (bf16*)carve((size_t)BATCH * 1024 * 2);
  bf16* histWa = (bf16*)carve((size_t)16 * BATCH * HDIM * 2);
  bf16* histWe = (bf16*)carve((size_t)16 * BATCH * HDIM * 2);
  bf16* hd1    = (bf16*)carve((size_t)BATCH * 256 * 2);

  // ---- setup ----
  build_x_kernel<<<(TSTEPS * BATCH * 64) / 256, 256, 0, stream>>>(inputs, xbuf, tdT);
  pack_wcombT_kernel<<<(NR * KA + 255) / 256, 256, 0, stream>>>(Wx, Uh, Wt, WxT, Wa, We, wcombT);
  pack_t_kernel<<<(512 * 512) / 256, 256, 0, stream>>>(Wb, wbwgT, 512, 512);
  pack_t_kernel<<<(512 * 512) / 256, 256, 0, stream>>>(Wg, wbwgT + (size_t)512 * 512, 512, 512);
  pack_t_kernel<<<(256 * 512) / 256, 256, 0, stream>>>(W1, w1T, 256, 512);
  setup_misc_kernel<<<1, 512, 0, stream>>>(init_proj, Wa, We, ba, sWa, sWe, baPad);
  zero_state_kernel<<<(BATCH * HDIM) / 256, 256, 0, stream>>>(cbuf, hbuf);

  // ---- recurrence: 3 kernels per step ----
#define ATTN_LAUNCH(KK)                                                              \
  case KK:                                                                           \
    attention_kernel<KK><<<BATCH / 4, 256, 0, stream>>>(hWbG, sWa, sWe, va, bh,      \
                                                        histWa, histWe, hbuf);       \
    break;

  for (int t = 0; t < TSTEPS; ++t) {
    bf16* waSlot = histWa + (size_t)((t + 15) & 15) * BATCH * HDIM;
    bf16* weSlot = histWe + (size_t)((t + 15) & 15) * BATCH * HDIM;
    gemm1_fused<<<512, 256, 0, stream>>>(
        xbuf + (size_t)t * BATCH * 64, hbuf, wcombT, tdT + (size_t)t * BATCH, bv, WtT, bT,
        cbuf, hcur, waSlot, weSlot);
    gemm2_kernel<<<512, 256, 0, stream>>>(hcur, wbwgT, baPad, hWbG);
    switch (t) {
      ATTN_LAUNCH(0) ATTN_LAUNCH(1) ATTN_LAUNCH(2) ATTN_LAUNCH(3)
      ATTN_LAUNCH(4) ATTN_LAUNCH(5) ATTN_LAUNCH(6) ATTN_LAUNCH(7)
      ATTN_LAUNCH(8) ATTN_LAUNCH(9) ATTN_LAUNCH(10) ATTN_LAUNCH(11)
      ATTN_LAUNCH(12) ATTN_LAUNCH(13) ATTN_LAUNCH(14) ATTN_LAUNCH(15)
    }
  }
#undef ATTN_LAUNCH

  // ---- head ----
  gemm_glds_kernel<64, 128><<<dim3(256 / 128, BATCH / 64), 256, 0, stream>>>(
      hbuf, 512, 512, hbuf, 512, w1T, 512, 3, nullptr, 0, nullptr, hd1, 256, b1);
  head_kernel<<<BATCH / 256, 256, 0, stream>>>(hd1, W2, b2, W3, b3, out);
}